// Round 9
// baseline (361.925 us; speedup 1.0000x reference)
//
#include <hip/hip_runtime.h>

#define DEVI __device__ __forceinline__

constexpr float SCALE = 0.0625f;   // 256^-0.5
constexpr float LN_EPS = 1e-5f;

DEVI float dot256(const float* w, const float* x){
  float4 A = make_float4(0.f,0.f,0.f,0.f);
  #pragma unroll 8
  for (int k = 0; k < 64; ++k){
    float4 w4 = *(const float4*)(w + k*4);
    float4 x4 = *(const float4*)(x + k*4);
    A.x += w4.x*x4.x; A.y += w4.y*x4.y; A.z += w4.z*x4.z; A.w += w4.w*x4.w;
  }
  return (A.x+A.y)+(A.z+A.w);
}

// ---------- helpers for the once-only initq path (proven rounds 4-8) ----------
DEVI float gemv_row(const float* __restrict__ W, const float4* __restrict__ xv4, int tid){
  const float4* wr = (const float4*)(W + (size_t)tid*256);
  float a0=0.f, a1=0.f, a2=0.f, a3=0.f;
  #pragma unroll 16
  for (int k = 0; k < 64; ++k){
    float4 w = wr[k];
    float4 x = xv4[k];
    a0 += w.x*x.x; a1 += w.y*x.y; a2 += w.z*x.z; a3 += w.w*x.w;
  }
  return (a0+a1)+(a2+a3);
}

DEVI float gemv_col(const float* __restrict__ W, const float4* __restrict__ xv4, int tid){
  const float* wc = W + tid;
  float a0=0.f, a1=0.f, a2=0.f, a3=0.f;
  #pragma unroll 8
  for (int e4 = 0; e4 < 64; ++e4){
    float4 x = xv4[e4];
    const float* p = wc + (size_t)e4*1024;
    a0 += x.x*p[0]; a1 += x.y*p[256]; a2 += x.z*p[512]; a3 += x.w*p[768];
  }
  return (a0+a1)+(a2+a3);
}

DEVI float block_ln(float x, const float* __restrict__ g, const float* __restrict__ be,
                    float* red, int tid, int lane, int wv){
  float v1 = x, v2 = x*x;
  #pragma unroll
  for (int o = 32; o; o >>= 1){ v1 += __shfl_xor(v1,o,64); v2 += __shfl_xor(v2,o,64); }
  if (lane == 0){ red[wv] = v1; red[4+wv] = v2; }
  __syncthreads();
  float mu = (red[0]+red[1]+red[2]+red[3]) * (1.f/256.f);
  float var = (red[4]+red[5]+red[6]+red[7]) * (1.f/256.f) - mu*mu;
  float inv = rsqrtf(var + LN_EPS);
  float r = (x - mu)*inv*g[tid] + be[tid];
  __syncthreads();
  return r;
}

// ---------------- kInitQ: slots init + zero accumulators + q-projection (once) ---------
__global__ __launch_bounds__(256) void k_initq(const float* __restrict__ noise,
    const float* __restrict__ smu, const float* __restrict__ slsig,
    float* __restrict__ slotsA, float* __restrict__ uacc, float* __restrict__ Zacc,
    const float* __restrict__ g_s, const float* __restrict__ be_s,
    const float* __restrict__ Wq, const float* __restrict__ Wk,
    const float* __restrict__ g_in, const float* __restrict__ be_in,
    float* __restrict__ qg, float* __restrict__ gqbq){
  __shared__ float4 xv4[64];
  __shared__ float red[8];
  float* xv = (float*)xv4;
  const int r = blockIdx.x, tid = threadIdx.x, s = r & 7;
  const int lane = tid & 63, wv = tid >> 6;
  float sl = smu[s*256 + tid] + expf(slsig[s*256 + tid]) * noise[r*256 + tid];
  slotsA[r*256 + tid] = sl;
  uacc[r*256 + tid] = 0.f;
  if (tid == 0) Zacc[r] = 0.f;
  float sn = block_ln(sl, g_s, be_s, red, tid, lane, wv);
  xv[tid] = sn;
  __syncthreads();
  float q = gemv_row(Wq, xv4, tid);
  __syncthreads();
  xv[tid] = q;
  __syncthreads();
  float qk = gemv_col(Wk + (size_t)s*65536, xv4, tid);
  float qgv = qk * g_in[tid] * SCALE;
  float bqv = qk * be_in[tid] * SCALE;
  qg[r*256 + tid] = qgv;
  float vq = qgv, vb = bqv;
  #pragma unroll
  for (int o = 32; o; o >>= 1){ vq += __shfl_xor(vq,o,64); vb += __shfl_xor(vb,o,64); }
  if (lane == 0){ red[wv] = vq; red[4+wv] = vb; }
  __syncthreads();
  if (tid == 0) gqbq[r*2+0] = red[0]+red[1]+red[2]+red[3];
  if (tid == 1) gqbq[r*2+1] = red[4]+red[5]+red[6]+red[7];
}

// ===== tiled stages (proven round 8): 256 blocks = 8 sg x 32 col-groups of 8 =====

__global__ __launch_bounds__(256) void k_gruF(const float* __restrict__ sin_,
    const float* __restrict__ uacc, const float* __restrict__ Zacc,
    const float* __restrict__ Wf, const float* __restrict__ b_ih,
    const float* __restrict__ ghb, float* __restrict__ hbuf){
  __shared__ float xs[16][260];
  __shared__ float ws[24][260];
  const int tid = threadIdx.x, bid = blockIdx.x;
  const int sg = bid >> 5, cgi = bid & 31, cbase = cgi * 8;
  #pragma unroll
  for (int i = 0; i < 4; ++i){
    int idx4 = tid + i*256, jj = idx4 >> 6, k4 = idx4 & 63;
    *(float4*)&xs[jj][k4*4] = *(const float4*)(uacc + ((size_t)(sg + 8*jj))*256 + k4*4);
  }
  #pragma unroll
  for (int i = 0; i < 6; ++i){
    int idx4 = tid + i*256, row = idx4 >> 6, k4 = idx4 & 63;
    int g = row >> 3, rr = row & 7;
    *(float4*)&ws[row][k4*4] =
      *(const float4*)(Wf + (size_t)(sg*3 + g)*65536 + ((size_t)(cbase + rr))*256 + k4*4);
  }
  __syncthreads();
  if (tid < 128){
    const int j = tid >> 3, cc = tid & 7, r = sg + 8*j, c = cbase + cc;
    float rZ = 1.f / Zacc[r];
    float ir_ = dot256(&ws[cc][0],    &xs[j][0]) * rZ + b_ih[c];
    float iz_ = dot256(&ws[8+cc][0],  &xs[j][0]) * rZ + b_ih[256 + c];
    float in_ = dot256(&ws[16+cc][0], &xs[j][0]) * rZ + b_ih[512 + c];
    float hr_ = ghb[((size_t)0*128 + r)*256 + c];
    float hz_ = ghb[((size_t)1*128 + r)*256 + c];
    float hn_ = ghb[((size_t)2*128 + r)*256 + c];
    float hp  = sin_[(size_t)r*256 + c];
    float rg = 1.f/(1.f + expf(-(ir_ + hr_)));
    float zg = 1.f/(1.f + expf(-(iz_ + hz_)));
    float ng = tanhf(in_ + rg*hn_);
    hbuf[(size_t)r*256 + c] = (1.f - zg)*ng + zg*hp;
  }
}

__global__ __launch_bounds__(256) void k_ffa(const float* __restrict__ hbuf,
    const float* __restrict__ g_ff, const float* __restrict__ be_ff,
    const float* __restrict__ W1, const float* __restrict__ b1,
    float* __restrict__ hid, float* __restrict__ uacc, float* __restrict__ Zacc){
  __shared__ float xs[16][260];
  __shared__ float ws[8][260];
  __shared__ float gA[256], gB[256];
  __shared__ float redA[16][17], redB[16][17];
  __shared__ float musL[16], invsL[16];
  const int tid = threadIdx.x, bid = blockIdx.x;
  const int sg = bid >> 5, cgi = bid & 31, cbase = cgi * 8;
  #pragma unroll
  for (int i = 0; i < 4; ++i){
    int idx4 = tid + i*256, jj = idx4 >> 6, k4 = idx4 & 63;
    *(float4*)&xs[jj][k4*4] = *(const float4*)(hbuf + ((size_t)(sg + 8*jj))*256 + k4*4);
  }
  #pragma unroll
  for (int i = 0; i < 2; ++i){
    int idx4 = tid + i*256, row = idx4 >> 6, k4 = idx4 & 63;
    *(float4*)&ws[row][k4*4] = *(const float4*)(W1 + ((size_t)(cbase + row))*256 + k4*4);
  }
  gA[tid] = g_ff[tid]; gB[tid] = be_ff[tid];
  __syncthreads();
  {
    int jr = tid >> 4, seg = tid & 15;
    float s1 = 0.f, s2 = 0.f;
    #pragma unroll
    for (int i = 0; i < 16; ++i){ float v = xs[jr][seg*16 + i]; s1 += v; s2 += v*v; }
    redA[jr][seg] = s1; redB[jr][seg] = s2;
    __syncthreads();
    if (tid < 16){
      float t1 = 0.f, t2 = 0.f;
      #pragma unroll
      for (int p = 0; p < 16; ++p){ t1 += redA[tid][p]; t2 += redB[tid][p]; }
      float mu = t1 * (1.f/256.f);
      float var = t2 * (1.f/256.f) - mu*mu;
      musL[tid] = mu; invsL[tid] = rsqrtf(var + LN_EPS);
    }
    __syncthreads();
    float mu = musL[jr], inv = invsL[jr];
    #pragma unroll
    for (int i = 0; i < 16; ++i){
      int k = seg*16 + i;
      xs[jr][k] = (xs[jr][k] - mu)*inv*gA[k] + gB[k];
    }
  }
  __syncthreads();
  if (tid < 128){
    const int j = tid >> 3, cc = tid & 7, r = sg + 8*j, c = cbase + cc;
    hid[(size_t)r*256 + c] = fmaxf(dot256(&ws[cc][0], &xs[j][0]) + b1[c], 0.f);
    uacc[(size_t)r*256 + c] = 0.f;
  }
  if (cgi == 0 && tid < 16) Zacc[sg + 8*tid] = 0.f;
}

__global__ __launch_bounds__(256) void k_ffb(const float* __restrict__ hid,
    const float* __restrict__ hbuf, const float* __restrict__ W2,
    const float* __restrict__ b2, float* __restrict__ sout,
    float* __restrict__ out_slots, float* __restrict__ gqbq, int last){
  __shared__ float xs[16][260];
  __shared__ float ws[8][260];
  const int tid = threadIdx.x, bid = blockIdx.x;
  const int sg = bid >> 5, cgi = bid & 31, cbase = cgi * 8;
  #pragma unroll
  for (int i = 0; i < 4; ++i){
    int idx4 = tid + i*256, jj = idx4 >> 6, k4 = idx4 & 63;
    *(float4*)&xs[jj][k4*4] = *(const float4*)(hid + ((size_t)(sg + 8*jj))*256 + k4*4);
  }
  #pragma unroll
  for (int i = 0; i < 2; ++i){
    int idx4 = tid + i*256, row = idx4 >> 6, k4 = idx4 & 63;
    *(float4*)&ws[row][k4*4] = *(const float4*)(W2 + ((size_t)(cbase + row))*256 + k4*4);
  }
  __syncthreads();
  if (tid < 128){
    const int j = tid >> 3, cc = tid & 7, r = sg + 8*j, c = cbase + cc;
    float out = hbuf[(size_t)r*256 + c] + dot256(&ws[cc][0], &xs[j][0]) + b2[c];
    sout[(size_t)r*256 + c] = out;
    if (last) out_slots[(size_t)r*256 + c] = out;
  }
  if (cgi == 0 && tid < 32)
    gqbq[(sg + 8*(tid>>1))*2 + (tid&1)] = 0.f;
}

__global__ __launch_bounds__(256) void k_lnqk(const float* __restrict__ sl,
    const float* __restrict__ g_s, const float* __restrict__ be_s,
    const float* __restrict__ Mt,
    const float* __restrict__ g_in, const float* __restrict__ be_in,
    float* __restrict__ qg, float* __restrict__ gqbq){
  __shared__ float xs[16][260];
  __shared__ float ws[8][260];
  __shared__ float gA[256], gB[256];
  __shared__ float redA[16][17], redB[16][17];
  __shared__ float musL[16], invsL[16];
  const int tid = threadIdx.x, bid = blockIdx.x;
  const int sg = bid >> 5, cgi = bid & 31, cbase = cgi * 8;
  #pragma unroll
  for (int i = 0; i < 4; ++i){
    int idx4 = tid + i*256, jj = idx4 >> 6, k4 = idx4 & 63;
    *(float4*)&xs[jj][k4*4] = *(const float4*)(sl + ((size_t)(sg + 8*jj))*256 + k4*4);
  }
  #pragma unroll
  for (int i = 0; i < 2; ++i){
    int idx4 = tid + i*256, row = idx4 >> 6, k4 = idx4 & 63;
    *(float4*)&ws[row][k4*4] =
      *(const float4*)(Mt + (size_t)sg*65536 + ((size_t)(cbase + row))*256 + k4*4);
  }
  gA[tid] = g_s[tid]; gB[tid] = be_s[tid];
  __syncthreads();
  {
    int jr = tid >> 4, seg = tid & 15;
    float s1 = 0.f, s2 = 0.f;
    #pragma unroll
    for (int i = 0; i < 16; ++i){ float v = xs[jr][seg*16 + i]; s1 += v; s2 += v*v; }
    redA[jr][seg] = s1; redB[jr][seg] = s2;
    __syncthreads();
    if (tid < 16){
      float t1 = 0.f, t2 = 0.f;
      #pragma unroll
      for (int p = 0; p < 16; ++p){ t1 += redA[tid][p]; t2 += redB[tid][p]; }
      float mu = t1 * (1.f/256.f);
      float var = t2 * (1.f/256.f) - mu*mu;
      musL[tid] = mu; invsL[tid] = rsqrtf(var + LN_EPS);
    }
    __syncthreads();
    float mu = musL[jr], inv = invsL[jr];
    #pragma unroll
    for (int i = 0; i < 16; ++i){
      int k = seg*16 + i;
      xs[jr][k] = (xs[jr][k] - mu)*inv*gA[k] + gB[k];
    }
  }
  __syncthreads();
  if (tid < 128){
    const int j = tid >> 3, cc = tid & 7, r = sg + 8*j, c = cbase + cc;
    float qk = dot256(&ws[cc][0], &xs[j][0]);
    float qgv = qk * g_in[c] * SCALE;
    float bqv = qk * be_in[c] * SCALE;
    qg[(size_t)r*256 + c] = qgv;
    float vq = qgv, vb = bqv;
    #pragma unroll
    for (int o = 1; o <= 4; o <<= 1){ vq += __shfl_xor(vq,o,64); vb += __shfl_xor(vb,o,64); }
    if (cc == 0){
      atomicAdd(&gqbq[r*2+0], vq);
      atomicAdd(&gqbq[r*2+1], vb);
    }
  }
}

// ---------------- K1: attn blocks 0..2047 (32-token tiles, emb staged in LDS)
//                  + gh blocks 2048..2815 + (it0 only) Wf/Mt GEMM blocks 2816..3327 ----
__global__ __launch_bounds__(256) void k_main_gh(const float* __restrict__ emb,
    const float* __restrict__ qg, const float* __restrict__ gqbq,
    const float* __restrict__ g_in, const float* __restrict__ be_in,
    float* __restrict__ uacc, float* __restrict__ Zacc,
    float* __restrict__ out_attn, int write_attn,
    const float* __restrict__ sin_, const float* __restrict__ W_hh,
    const float* __restrict__ b_hh, float* __restrict__ ghb,
    const float* __restrict__ W_ih, const float* __restrict__ Wv,
    const float* __restrict__ Wk, const float* __restrict__ Wq,
    float* __restrict__ Wf, float* __restrict__ Mt){
  __shared__ float SM[12288];                  // 48 KB union
  __shared__ float aL[256];
  __shared__ float red2[2][8][4];
  __shared__ float Zs[8], A2s[8], GqL[8], BqL[8];

  const int tid = threadIdx.x, lane = tid & 63, wv = tid >> 6;
  const int blk = blockIdx.x;

  if (blk >= 2816){
    // ---- Wf/Mt GEMM (it0 only): C[i][j] = sum_e At[e][i]*Bs[e][j]; 64x64, K-slice 64 --
    float (*At)[68] = (float(*)[68])SM;
    float (*Bs)[68] = (float(*)[68])(SM + 4352);
    const int gb = blk - 2816;
    const bool isWf = gb < 384;
    const float *A, *B; float *C;
    int tile;
    if (isWf){
      int gm = gb >> 4; tile = gb & 15;        // gm = s*3+g
      A = W_ih + (size_t)(gm % 3) * 65536;     // [i][e] -> transpose load
      B = Wv   + (size_t)(gm / 3) * 65536;     // [e][j]
      C = Wf   + (size_t)gm * 65536;
    } else {
      int gm = (gb - 384) >> 4; tile = (gb - 384) & 15;
      A = Wk + (size_t)gm * 65536;             // [e][c]
      B = Wq;                                  // [e][d]
      C = Mt + (size_t)gm * 65536;
    }
    const int i0 = (tile >> 2) * 64, j0 = (tile & 3) * 64;
    const int ty = tid >> 4, tx = tid & 15;
    float acc[4][4];
    #pragma unroll
    for (int a = 0; a < 4; ++a)
      #pragma unroll
      for (int b = 0; b < 4; ++b) acc[a][b] = 0.f;
    for (int ko = 0; ko < 256; ko += 64){
      #pragma unroll
      for (int p = 0; p < 4; ++p){
        int idx4 = tid + p*256;
        int e = idx4 >> 4, jl4 = idx4 & 15;
        *(float4*)&Bs[e][jl4*4] = *(const float4*)(B + (size_t)(ko+e)*256 + j0 + jl4*4);
      }
      if (isWf){
        #pragma unroll
        for (int p = 0; p < 4; ++p){
          int idx4 = tid + p*256;
          int il = idx4 >> 4, e4 = idx4 & 15;
          float4 w = *(const float4*)(A + (size_t)(i0+il)*256 + ko + e4*4);
          At[e4*4+0][il] = w.x; At[e4*4+1][il] = w.y;
          At[e4*4+2][il] = w.z; At[e4*4+3][il] = w.w;
        }
      } else {
        #pragma unroll
        for (int p = 0; p < 4; ++p){
          int idx4 = tid + p*256;
          int e = idx4 >> 4, il4 = idx4 & 15;
          *(float4*)&At[e][il4*4] = *(const float4*)(A + (size_t)(ko+e)*256 + i0 + il4*4);
        }
      }
      __syncthreads();
      #pragma unroll 4
      for (int e = 0; e < 64; ++e){
        float4 a4 = *(const float4*)&At[e][ty*4];
        float4 b4 = *(const float4*)&Bs[e][tx*4];
        acc[0][0]+=a4.x*b4.x; acc[0][1]+=a4.x*b4.y; acc[0][2]+=a4.x*b4.z; acc[0][3]+=a4.x*b4.w;
        acc[1][0]+=a4.y*b4.x; acc[1][1]+=a4.y*b4.y; acc[1][2]+=a4.y*b4.z; acc[1][3]+=a4.y*b4.w;
        acc[2][0]+=a4.z*b4.x; acc[2][1]+=a4.z*b4.y; acc[2][2]+=a4.z*b4.z; acc[2][3]+=a4.z*b4.w;
        acc[3][0]+=a4.w*b4.x; acc[3][1]+=a4.w*b4.y; acc[3][2]+=a4.w*b4.z; acc[3][3]+=a4.w*b4.w;
      }
      __syncthreads();
    }
    #pragma unroll
    for (int ii = 0; ii < 4; ++ii)
      *(float4*)(C + (size_t)(i0+ty*4+ii)*256 + j0 + tx*4) =
        make_float4(acc[ii][0], acc[ii][1], acc[ii][2], acc[ii][3]);
    return;
  }

  if (blk >= 2048){
    // ---- gh: gh[g][r][cbase..+8) = sin@W_hh[g]^T + b_hh[g]  (round-8 proven) ----
    float (*xs)[260]  = (float(*)[260])SM;
    float (*wsh)[260] = (float(*)[260])(SM + 4160);
    const int idx = blk - 2048;          // 0..767
    const int g = idx >> 8, sub = idx & 255;
    const int sg = sub >> 5, cgi = sub & 31, cbase = cgi * 8;
    #pragma unroll
    for (int i = 0; i < 4; ++i){
      int idx4 = tid + i*256, jj = idx4 >> 6, k4 = idx4 & 63;
      *(float4*)&xs[jj][k4*4] = *(const float4*)(sin_ + ((size_t)(sg + 8*jj))*256 + k4*4);
    }
    #pragma unroll
    for (int i = 0; i < 2; ++i){
      int idx4 = tid + i*256, row = idx4 >> 6, k4 = idx4 & 63;
      *(float4*)&wsh[row][k4*4] =
        *(const float4*)(W_hh + (size_t)g*65536 + ((size_t)(cbase + row))*256 + k4*4);
    }
    __syncthreads();
    if (tid < 128){
      const int j = tid >> 3, cc = tid & 7, r = sg + 8*j, c = cbase + cc;
      ghb[((size_t)g*128 + r)*256 + c] = dot256(&wsh[cc][0], &xs[j][0]) + b_hh[g*256 + c];
    }
    return;
  }

  // ---- attention: 32-token tile, emb staged once into LDS ----
  float* const tileL = SM;                     // [32][256] = 32 KB
  float* const qgL = SM + 8192;                // [2048] phase 1 (bank-swizzled)
  float* const avL = SM + 10240;               // [256]  phase 1
  float4* const Sp4 = (float4*)(SM + 8192);    // [1024] float4, phase 2 (overlays qgL/avL)

  const int b = blk >> 7, tile = blk & 127;
  const int n0 = tile * 32;

  { // stage queries with per-qq rotation so the 8 qq-chunks hit distinct banks
    const float4* src = (const float4*)(qg + (size_t)b * 2048);
    float4* dst = (float4*)qgL;
    #pragma unroll
    for (int k = 0; k < 2; ++k){
      int w = tid + k*256;                 // 0..511
      int s = w >> 6, f = w & 63, qq = f >> 3, j = f & 7;
      dst[s*64 + qq*8 + ((j + qq) & 7)] = src[w];
    }
  }
  if (tid < 8){
    GqL[tid] = gqbq[(b*8 + tid)*2 + 0];
    BqL[tid] = gqbq[(b*8 + tid)*2 + 1];
  }
  __syncthreads();

  const int qq = tid & 7;    // 32-col chunk
  const int t  = tid >> 3;   // token 0..31
  float zsum[8], z2sum[8];
  #pragma unroll
  for (int s = 0; s < 8; ++s){ zsum[s] = 0.f; z2sum[s] = 0.f; }

  {
    const float4* xrow = (const float4*)(emb + ((size_t)(b*4096 + n0 + t))*256 + qq*32);
    float4 xv4[8];
    #pragma unroll
    for (int j = 0; j < 8; ++j) xv4[j] = xrow[j];
    { // stage emb tile for phase 2 (single global read of emb)
      float4* tdst = (float4*)&tileL[t*256 + qq*32];
      #pragma unroll
      for (int j = 0; j < 8; ++j) tdst[j] = xv4[j];
    }
    float s1 = 0.f, s2 = 0.f, acc[8];
    #pragma unroll
    for (int s = 0; s < 8; ++s) acc[s] = 0.f;
    #pragma unroll
    for (int j = 0; j < 8; ++j){
      float4 u = xv4[j];
      s1 += (u.x+u.y)+(u.z+u.w);
      s2 += u.x*u.x+u.y*u.y+u.z*u.z+u.w*u.w;
      const float* qb = qgL + qq*32 + ((j + qq) & 7)*4;
      #pragma unroll
      for (int s = 0; s < 8; ++s){
        float4 q0 = *(const float4*)(qb + s*256);
        acc[s] += u.x*q0.x + u.y*q0.y + u.z*q0.z + u.w*q0.w;
      }
    }
    #pragma unroll
    for (int o = 1; o <= 4; o <<= 1){
      s1 += __shfl_xor(s1,o,64); s2 += __shfl_xor(s2,o,64);
      #pragma unroll
      for (int s = 0; s < 8; ++s) acc[s] += __shfl_xor(acc[s],o,64);
    }
    float mu = s1 * (1.f/256.f);
    float var = s2 * (1.f/256.f) - mu*mu;
    float inv = rsqrtf(var + LN_EPS);
    float dv[8], mx = -1e30f;
    #pragma unroll
    for (int s = 0; s < 8; ++s){
      dv[s] = inv * (acc[s] - mu * GqL[s]) + BqL[s];
      mx = fmaxf(mx, dv[s]);
    }
    float den = 0.f;
    #pragma unroll
    for (int s = 0; s < 8; ++s){ dv[s] = expf(dv[s] - mx); den += dv[s]; }
    float rden = 1.f / den;
    #pragma unroll
    for (int s = 0; s < 8; ++s){
      float at = dv[s] * rden;       // attn (softmax over slots)
      float av = at * inv;           // attn * inv (LN folded)
      if (qq == 0){ avL[s*32 + t] = at; aL[s*32 + t] = av; }
      zsum[s] += at;                 // each token counted by its 8 qq-lanes
      z2sum[s] += av * mu;
    }
  }
  #pragma unroll
  for (int s = 0; s < 8; ++s){
    #pragma unroll
    for (int o = 32; o; o >>= 1){
      zsum[s] += __shfl_xor(zsum[s], o, 64);
      z2sum[s] += __shfl_xor(z2sum[s], o, 64);
    }
  }
  if (lane == 0){
    #pragma unroll
    for (int s = 0; s < 8; ++s){ red2[0][s][wv] = zsum[s]*0.125f; red2[1][s][wv] = z2sum[s]*0.125f; }
  }
  __syncthreads();
  if (tid < 8){
    Zs[tid]  = red2[0][tid][0]+red2[0][tid][1]+red2[0][tid][2]+red2[0][tid][3];
    A2s[tid] = red2[1][tid][0]+red2[1][tid][1]+red2[1][tid][2]+red2[1][tid][3];
  }
  if (write_attn){
    int s = tid >> 5, tk = tid & 31;
    out_attn[((size_t)(b*8 + s))*4096 + n0 + tk] = avL[s*32 + tk];
  }
  __syncthreads();                   // avL/qgL dead past here; Sp4 takes over
  { // phase 2: token-weighted accumulation from the LDS tile (no global re-read)
    const int r2 = tid >> 7, sh = (tid >> 6) & 1, cq = tid & 63;
    float4 S1[4];
    #pragma unroll
    for (int so = 0; so < 4; ++so) S1[so] = make_float4(0.f,0.f,0.f,0.f);
    #pragma unroll 4
    for (int i = 0; i < 16; ++i){
      int tt = r2 + i*2;
      float4 x4 = *(const float4*)&tileL[tt*256 + cq*4];
      #pragma unroll
      for (int so = 0; so < 4; ++so){
        float a = aL[(sh*4+so)*32 + tt];   // wave-uniform broadcast
        S1[so].x += a*x4.x; S1[so].y += a*x4.y; S1[so].z += a*x4.z; S1[so].w += a*x4.w;
      }
    }
    #pragma unroll
    for (int so = 0; so < 4; ++so) Sp4[(r2*8 + sh*4+so)*64 + cq] = S1[so];
  }
  __syncthreads();
  { // final: sum 2 partials per (s,c), atomically accumulate (s staggered)
    const int c = tid;
    const float* Sp = (const float*)Sp4;
    float gc = g_in[c], bc = be_in[c];
    float* dst = uacc + ((size_t)b*8)*256 + c;
    #pragma unroll
    for (int si = 0; si < 8; ++si){
      int s = (si + blk) & 7;
      float v = Sp[(0*8+s)*256 + c] + Sp[(1*8+s)*256 + c];
      atomicAdd(&dst[s*256], gc * (v - A2s[s]) + bc * Zs[s]);
    }
    if (tid < 8) atomicAdd(&Zacc[b*8 + tid], Zs[tid]);
  }
}

extern "C" void kernel_launch(void* const* d_in, const int* in_sizes, int n_in,
                              void* d_out, int out_size, void* d_ws, size_t ws_size,
                              hipStream_t stream){
  const float* emb   = (const float*)d_in[0];
  const float* noise = (const float*)d_in[1];
  const float* smu   = (const float*)d_in[2];
  const float* slsig = (const float*)d_in[3];
  const float* Wk    = (const float*)d_in[4];
  const float* Wq    = (const float*)d_in[5];
  const float* Wv    = (const float*)d_in[6];
  const float* W_ih  = (const float*)d_in[7];
  const float* W_hh  = (const float*)d_in[8];
  const float* b_ih  = (const float*)d_in[9];
  const float* b_hh  = (const float*)d_in[10];
  const float* W1    = (const float*)d_in[11];
  const float* b1    = (const float*)d_in[12];
  const float* W2    = (const float*)d_in[13];
  const float* b2    = (const float*)d_in[14];
  const float* g_in  = (const float*)d_in[15];
  const float* be_in = (const float*)d_in[16];
  const float* g_s   = (const float*)d_in[17];
  const float* be_s  = (const float*)d_in[18];
  const float* g_ff  = (const float*)d_in[19];
  const float* be_ff = (const float*)d_in[20];

  float* ws     = (float*)d_ws;
  float* slotsA = ws;                 // 32768
  float* slotsB = ws + 32768;         // 32768
  float* qg     = ws + 65536;         // 32768
  float* gqbq   = ws + 98304;         // 256
  float* uacc   = ws + 98560;         // 32768
  float* Zacc   = ws + 131328;        // 128
  float* ghb    = ws + 131456;        // 98304
  float* hbuf   = ws + 229760;        // 32768
  float* hid    = ws + 262528;        // 32768
  float* Wf     = ws + 295296;        // 1572864 (6 MB)
  float* Mt     = ws + 1868160;       // 524288  (2 MB)

  float* out_slots = (float*)d_out;
  float* out_attn  = out_slots + 32768;
  const int has_attn = (out_size >= 32768 + 16*8*4096);

  k_initq<<<dim3(128), dim3(256), 0, stream>>>(noise, smu, slsig, slotsA, uacc, Zacc,
      g_s, be_s, Wq, Wk, g_in, be_in, qg, gqbq);
  for (int it = 0; it < 3; ++it){
    int last = (it == 2);
    float* sin  = (it == 1) ? slotsB : slotsA;
    float* sout = (it == 1) ? slotsA : slotsB;
    int grid = (it == 0) ? 3328 : 2816;   // it0 carries the Wf/Mt precompute blocks
    k_main_gh<<<dim3(grid), dim3(256), 0, stream>>>(emb, qg, gqbq, g_in, be_in,
        uacc, Zacc, out_attn, last && has_attn, sin, W_hh, b_hh, ghb,
        W_ih, Wv, Wk, Wq, Wf, Mt);
    k_gruF<<<dim3(256), dim3(256), 0, stream>>>(sin, uacc, Zacc, Wf, b_ih, ghb, hbuf);
    k_ffa<<<dim3(256), dim3(256), 0, stream>>>(hbuf, g_ff, be_ff, W1, b1, hid, uacc, Zacc);
    k_ffb<<<dim3(256), dim3(256), 0, stream>>>(hid, hbuf, W2, b2, sout, out_slots,
        gqbq, last);
    if (!last)
      k_lnqk<<<dim3(256), dim3(256), 0, stream>>>(sout, g_s, be_s, Mt, g_in, be_in,
          qg, gqbq);
  }
}

// Round 10
// 326.875 us; speedup vs baseline: 1.1072x; 1.1072x over previous
//
#include <hip/hip_runtime.h>

#define DEVI __device__ __forceinline__

constexpr float SCALE = 0.0625f;   // 256^-0.5
constexpr float LN_EPS = 1e-5f;

DEVI float dot256(const float* w, const float* x){
  float4 A = make_float4(0.f,0.f,0.f,0.f);
  #pragma unroll 8
  for (int k = 0; k < 64; ++k){
    float4 w4 = *(const float4*)(w + k*4);
    float4 x4 = *(const float4*)(x + k*4);
    A.x += w4.x*x4.x; A.y += w4.y*x4.y; A.z += w4.z*x4.z; A.w += w4.w*x4.w;
  }
  return (A.x+A.y)+(A.z+A.w);
}

// ---------- helpers for the once-only initq path (proven rounds 4-9) ----------
DEVI float gemv_row(const float* __restrict__ W, const float4* __restrict__ xv4, int tid){
  const float4* wr = (const float4*)(W + (size_t)tid*256);
  float a0=0.f, a1=0.f, a2=0.f, a3=0.f;
  #pragma unroll 16
  for (int k = 0; k < 64; ++k){
    float4 w = wr[k];
    float4 x = xv4[k];
    a0 += w.x*x.x; a1 += w.y*x.y; a2 += w.z*x.z; a3 += w.w*x.w;
  }
  return (a0+a1)+(a2+a3);
}

DEVI float gemv_col(const float* __restrict__ W, const float4* __restrict__ xv4, int tid){
  const float* wc = W + tid;
  float a0=0.f, a1=0.f, a2=0.f, a3=0.f;
  #pragma unroll 8
  for (int e4 = 0; e4 < 64; ++e4){
    float4 x = xv4[e4];
    const float* p = wc + (size_t)e4*1024;
    a0 += x.x*p[0]; a1 += x.y*p[256]; a2 += x.z*p[512]; a3 += x.w*p[768];
  }
  return (a0+a1)+(a2+a3);
}

DEVI float block_ln(float x, const float* __restrict__ g, const float* __restrict__ be,
                    float* red, int tid, int lane, int wv){
  float v1 = x, v2 = x*x;
  #pragma unroll
  for (int o = 32; o; o >>= 1){ v1 += __shfl_xor(v1,o,64); v2 += __shfl_xor(v2,o,64); }
  if (lane == 0){ red[wv] = v1; red[4+wv] = v2; }
  __syncthreads();
  float mu = (red[0]+red[1]+red[2]+red[3]) * (1.f/256.f);
  float var = (red[4]+red[5]+red[6]+red[7]) * (1.f/256.f) - mu*mu;
  float inv = rsqrtf(var + LN_EPS);
  float r = (x - mu)*inv*g[tid] + be[tid];
  __syncthreads();
  return r;
}

// ---------------- kInitQ: slots init + zero accumulators + q-projection (once) ---------
__global__ __launch_bounds__(256) void k_initq(const float* __restrict__ noise,
    const float* __restrict__ smu, const float* __restrict__ slsig,
    float* __restrict__ slotsA, float* __restrict__ uacc, float* __restrict__ Zacc,
    const float* __restrict__ g_s, const float* __restrict__ be_s,
    const float* __restrict__ Wq, const float* __restrict__ Wk,
    const float* __restrict__ g_in, const float* __restrict__ be_in,
    float* __restrict__ qg, float* __restrict__ gqbq){
  __shared__ float4 xv4[64];
  __shared__ float red[8];
  float* xv = (float*)xv4;
  const int r = blockIdx.x, tid = threadIdx.x, s = r & 7;
  const int lane = tid & 63, wv = tid >> 6;
  float sl = smu[s*256 + tid] + expf(slsig[s*256 + tid]) * noise[r*256 + tid];
  slotsA[r*256 + tid] = sl;
  uacc[r*256 + tid] = 0.f;
  if (tid == 0) Zacc[r] = 0.f;
  float sn = block_ln(sl, g_s, be_s, red, tid, lane, wv);
  xv[tid] = sn;
  __syncthreads();
  float q = gemv_row(Wq, xv4, tid);
  __syncthreads();
  xv[tid] = q;
  __syncthreads();
  float qk = gemv_col(Wk + (size_t)s*65536, xv4, tid);
  float qgv = qk * g_in[tid] * SCALE;
  float bqv = qk * be_in[tid] * SCALE;
  qg[r*256 + tid] = qgv;
  float vq = qgv, vb = bqv;
  #pragma unroll
  for (int o = 32; o; o >>= 1){ vq += __shfl_xor(vq,o,64); vb += __shfl_xor(vb,o,64); }
  if (lane == 0){ red[wv] = vq; red[4+wv] = vb; }
  __syncthreads();
  if (tid == 0) gqbq[r*2+0] = red[0]+red[1]+red[2]+red[3];
  if (tid == 1) gqbq[r*2+1] = red[4]+red[5]+red[6]+red[7];
}

// ===== tiled stages (proven round 8): 256 blocks = 8 sg x 32 col-groups of 8 =====

__global__ __launch_bounds__(256) void k_gruF(const float* __restrict__ sin_,
    const float* __restrict__ uacc, const float* __restrict__ Zacc,
    const float* __restrict__ Wf, const float* __restrict__ b_ih,
    const float* __restrict__ ghb, float* __restrict__ hbuf){
  __shared__ float xs[16][260];
  __shared__ float ws[24][260];
  const int tid = threadIdx.x, bid = blockIdx.x;
  const int sg = bid >> 5, cgi = bid & 31, cbase = cgi * 8;
  #pragma unroll
  for (int i = 0; i < 4; ++i){
    int idx4 = tid + i*256, jj = idx4 >> 6, k4 = idx4 & 63;
    *(float4*)&xs[jj][k4*4] = *(const float4*)(uacc + ((size_t)(sg + 8*jj))*256 + k4*4);
  }
  #pragma unroll
  for (int i = 0; i < 6; ++i){
    int idx4 = tid + i*256, row = idx4 >> 6, k4 = idx4 & 63;
    int g = row >> 3, rr = row & 7;
    *(float4*)&ws[row][k4*4] =
      *(const float4*)(Wf + (size_t)(sg*3 + g)*65536 + ((size_t)(cbase + rr))*256 + k4*4);
  }
  __syncthreads();
  if (tid < 128){
    const int j = tid >> 3, cc = tid & 7, r = sg + 8*j, c = cbase + cc;
    float rZ = 1.f / Zacc[r];
    float ir_ = dot256(&ws[cc][0],    &xs[j][0]) * rZ + b_ih[c];
    float iz_ = dot256(&ws[8+cc][0],  &xs[j][0]) * rZ + b_ih[256 + c];
    float in_ = dot256(&ws[16+cc][0], &xs[j][0]) * rZ + b_ih[512 + c];
    float hr_ = ghb[((size_t)0*128 + r)*256 + c];
    float hz_ = ghb[((size_t)1*128 + r)*256 + c];
    float hn_ = ghb[((size_t)2*128 + r)*256 + c];
    float hp  = sin_[(size_t)r*256 + c];
    float rg = 1.f/(1.f + expf(-(ir_ + hr_)));
    float zg = 1.f/(1.f + expf(-(iz_ + hz_)));
    float ng = tanhf(in_ + rg*hn_);
    hbuf[(size_t)r*256 + c] = (1.f - zg)*ng + zg*hp;
  }
}

__global__ __launch_bounds__(256) void k_ffa(const float* __restrict__ hbuf,
    const float* __restrict__ g_ff, const float* __restrict__ be_ff,
    const float* __restrict__ W1, const float* __restrict__ b1,
    float* __restrict__ hid, float* __restrict__ uacc, float* __restrict__ Zacc){
  __shared__ float xs[16][260];
  __shared__ float ws[8][260];
  __shared__ float gA[256], gB[256];
  __shared__ float redA[16][17], redB[16][17];
  __shared__ float musL[16], invsL[16];
  const int tid = threadIdx.x, bid = blockIdx.x;
  const int sg = bid >> 5, cgi = bid & 31, cbase = cgi * 8;
  #pragma unroll
  for (int i = 0; i < 4; ++i){
    int idx4 = tid + i*256, jj = idx4 >> 6, k4 = idx4 & 63;
    *(float4*)&xs[jj][k4*4] = *(const float4*)(hbuf + ((size_t)(sg + 8*jj))*256 + k4*4);
  }
  #pragma unroll
  for (int i = 0; i < 2; ++i){
    int idx4 = tid + i*256, row = idx4 >> 6, k4 = idx4 & 63;
    *(float4*)&ws[row][k4*4] = *(const float4*)(W1 + ((size_t)(cbase + row))*256 + k4*4);
  }
  gA[tid] = g_ff[tid]; gB[tid] = be_ff[tid];
  __syncthreads();
  {
    int jr = tid >> 4, seg = tid & 15;
    float s1 = 0.f, s2 = 0.f;
    #pragma unroll
    for (int i = 0; i < 16; ++i){ float v = xs[jr][seg*16 + i]; s1 += v; s2 += v*v; }
    redA[jr][seg] = s1; redB[jr][seg] = s2;
    __syncthreads();
    if (tid < 16){
      float t1 = 0.f, t2 = 0.f;
      #pragma unroll
      for (int p = 0; p < 16; ++p){ t1 += redA[tid][p]; t2 += redB[tid][p]; }
      float mu = t1 * (1.f/256.f);
      float var = t2 * (1.f/256.f) - mu*mu;
      musL[tid] = mu; invsL[tid] = rsqrtf(var + LN_EPS);
    }
    __syncthreads();
    float mu = musL[jr], inv = invsL[jr];
    #pragma unroll
    for (int i = 0; i < 16; ++i){
      int k = seg*16 + i;
      xs[jr][k] = (xs[jr][k] - mu)*inv*gA[k] + gB[k];
    }
  }
  __syncthreads();
  if (tid < 128){
    const int j = tid >> 3, cc = tid & 7, r = sg + 8*j, c = cbase + cc;
    hid[(size_t)r*256 + c] = fmaxf(dot256(&ws[cc][0], &xs[j][0]) + b1[c], 0.f);
    uacc[(size_t)r*256 + c] = 0.f;
  }
  if (cgi == 0 && tid < 16) Zacc[sg + 8*tid] = 0.f;
}

__global__ __launch_bounds__(256) void k_ffb(const float* __restrict__ hid,
    const float* __restrict__ hbuf, const float* __restrict__ W2,
    const float* __restrict__ b2, float* __restrict__ sout,
    float* __restrict__ out_slots, float* __restrict__ gqbq, int last){
  __shared__ float xs[16][260];
  __shared__ float ws[8][260];
  const int tid = threadIdx.x, bid = blockIdx.x;
  const int sg = bid >> 5, cgi = bid & 31, cbase = cgi * 8;
  #pragma unroll
  for (int i = 0; i < 4; ++i){
    int idx4 = tid + i*256, jj = idx4 >> 6, k4 = idx4 & 63;
    *(float4*)&xs[jj][k4*4] = *(const float4*)(hid + ((size_t)(sg + 8*jj))*256 + k4*4);
  }
  #pragma unroll
  for (int i = 0; i < 2; ++i){
    int idx4 = tid + i*256, row = idx4 >> 6, k4 = idx4 & 63;
    *(float4*)&ws[row][k4*4] = *(const float4*)(W2 + ((size_t)(cbase + row))*256 + k4*4);
  }
  __syncthreads();
  if (tid < 128){
    const int j = tid >> 3, cc = tid & 7, r = sg + 8*j, c = cbase + cc;
    float out = hbuf[(size_t)r*256 + c] + dot256(&ws[cc][0], &xs[j][0]) + b2[c];
    sout[(size_t)r*256 + c] = out;
    if (last) out_slots[(size_t)r*256 + c] = out;
  }
  if (cgi == 0 && tid < 32)
    gqbq[(sg + 8*(tid>>1))*2 + (tid&1)] = 0.f;
}

__global__ __launch_bounds__(256) void k_lnqk(const float* __restrict__ sl,
    const float* __restrict__ g_s, const float* __restrict__ be_s,
    const float* __restrict__ Mt,
    const float* __restrict__ g_in, const float* __restrict__ be_in,
    float* __restrict__ qg, float* __restrict__ gqbq){
  __shared__ float xs[16][260];
  __shared__ float ws[8][260];
  __shared__ float gA[256], gB[256];
  __shared__ float redA[16][17], redB[16][17];
  __shared__ float musL[16], invsL[16];
  const int tid = threadIdx.x, bid = blockIdx.x;
  const int sg = bid >> 5, cgi = bid & 31, cbase = cgi * 8;
  #pragma unroll
  for (int i = 0; i < 4; ++i){
    int idx4 = tid + i*256, jj = idx4 >> 6, k4 = idx4 & 63;
    *(float4*)&xs[jj][k4*4] = *(const float4*)(sl + ((size_t)(sg + 8*jj))*256 + k4*4);
  }
  #pragma unroll
  for (int i = 0; i < 2; ++i){
    int idx4 = tid + i*256, row = idx4 >> 6, k4 = idx4 & 63;
    *(float4*)&ws[row][k4*4] =
      *(const float4*)(Mt + (size_t)sg*65536 + ((size_t)(cbase + row))*256 + k4*4);
  }
  gA[tid] = g_s[tid]; gB[tid] = be_s[tid];
  __syncthreads();
  {
    int jr = tid >> 4, seg = tid & 15;
    float s1 = 0.f, s2 = 0.f;
    #pragma unroll
    for (int i = 0; i < 16; ++i){ float v = xs[jr][seg*16 + i]; s1 += v; s2 += v*v; }
    redA[jr][seg] = s1; redB[jr][seg] = s2;
    __syncthreads();
    if (tid < 16){
      float t1 = 0.f, t2 = 0.f;
      #pragma unroll
      for (int p = 0; p < 16; ++p){ t1 += redA[tid][p]; t2 += redB[tid][p]; }
      float mu = t1 * (1.f/256.f);
      float var = t2 * (1.f/256.f) - mu*mu;
      musL[tid] = mu; invsL[tid] = rsqrtf(var + LN_EPS);
    }
    __syncthreads();
    float mu = musL[jr], inv = invsL[jr];
    #pragma unroll
    for (int i = 0; i < 16; ++i){
      int k = seg*16 + i;
      xs[jr][k] = (xs[jr][k] - mu)*inv*gA[k] + gB[k];
    }
  }
  __syncthreads();
  if (tid < 128){
    const int j = tid >> 3, cc = tid & 7, r = sg + 8*j, c = cbase + cc;
    float qk = dot256(&ws[cc][0], &xs[j][0]);
    float qgv = qk * g_in[c] * SCALE;
    float bqv = qk * be_in[c] * SCALE;
    qg[(size_t)r*256 + c] = qgv;
    float vq = qgv, vb = bqv;
    #pragma unroll
    for (int o = 1; o <= 4; o <<= 1){ vq += __shfl_xor(vq,o,64); vb += __shfl_xor(vb,o,64); }
    if (cc == 0){
      atomicAdd(&gqbq[r*2+0], vq);
      atomicAdd(&gqbq[r*2+1], vb);
    }
  }
}

// ---------------- K1: attn blocks 0..1023 (round-8 proven, 64-token tiles)
//                  + gh blocks 1024..1791 + (it0 only) Wf/Mt GEMM blocks 1792..2303 ----
__global__ __launch_bounds__(256) void k_main_gh(const float* __restrict__ emb,
    const float* __restrict__ qg, const float* __restrict__ gqbq,
    const float* __restrict__ g_in, const float* __restrict__ be_in,
    float* __restrict__ uacc, float* __restrict__ Zacc,
    float* __restrict__ out_attn, int write_attn,
    const float* __restrict__ sin_, const float* __restrict__ W_hh,
    const float* __restrict__ b_hh, float* __restrict__ ghb,
    const float* __restrict__ W_ih, const float* __restrict__ Wv,
    const float* __restrict__ Wk, const float* __restrict__ Wq,
    float* __restrict__ Wf, float* __restrict__ Mt){
  __shared__ float U[8704];                    // 34 KB union
  __shared__ float aL[512];
  __shared__ float red2[2][8][4];
  __shared__ float Zs[8], A2s[8], GqL[8], BqL[8];

  const int tid = threadIdx.x, lane = tid & 63, wv = tid >> 6;
  const int blk = blockIdx.x;

  if (blk >= 1792){
    // ---- Wf/Mt GEMM (it0 only): C[i][j] = sum_e At[e][i]*Bs[e][j]; 64x64, K-slice 64 --
    float (*At)[68] = (float(*)[68])U;             // [64][68]
    float (*Bs)[68] = (float(*)[68])(U + 4352);    // [64][68]
    const int gb = blk - 1792;
    const bool isWf = gb < 384;
    const float *A, *B; float *C;
    int tile;
    if (isWf){
      int gm = gb >> 4; tile = gb & 15;        // gm = s*3+g
      A = W_ih + (size_t)(gm % 3) * 65536;     // [i][e] -> transpose load
      B = Wv   + (size_t)(gm / 3) * 65536;     // [e][j]
      C = Wf   + (size_t)gm * 65536;
    } else {
      int gm = (gb - 384) >> 4; tile = (gb - 384) & 15;
      A = Wk + (size_t)gm * 65536;             // [e][c]
      B = Wq;                                  // [e][d]
      C = Mt + (size_t)gm * 65536;
    }
    const int i0 = (tile >> 2) * 64, j0 = (tile & 3) * 64;
    const int ty = tid >> 4, tx = tid & 15;
    float acc[4][4];
    #pragma unroll
    for (int a = 0; a < 4; ++a)
      #pragma unroll
      for (int b = 0; b < 4; ++b) acc[a][b] = 0.f;
    for (int ko = 0; ko < 256; ko += 64){
      #pragma unroll
      for (int p = 0; p < 4; ++p){
        int idx4 = tid + p*256;
        int e = idx4 >> 4, jl4 = idx4 & 15;
        *(float4*)&Bs[e][jl4*4] = *(const float4*)(B + (size_t)(ko+e)*256 + j0 + jl4*4);
      }
      if (isWf){
        #pragma unroll
        for (int p = 0; p < 4; ++p){
          int idx4 = tid + p*256;
          int il = idx4 >> 4, e4 = idx4 & 15;
          float4 w = *(const float4*)(A + (size_t)(i0+il)*256 + ko + e4*4);
          At[e4*4+0][il] = w.x; At[e4*4+1][il] = w.y;
          At[e4*4+2][il] = w.z; At[e4*4+3][il] = w.w;
        }
      } else {
        #pragma unroll
        for (int p = 0; p < 4; ++p){
          int idx4 = tid + p*256;
          int e = idx4 >> 4, il4 = idx4 & 15;
          *(float4*)&At[e][il4*4] = *(const float4*)(A + (size_t)(ko+e)*256 + i0 + il4*4);
        }
      }
      __syncthreads();
      #pragma unroll 4
      for (int e = 0; e < 64; ++e){
        float4 a4 = *(const float4*)&At[e][ty*4];
        float4 b4 = *(const float4*)&Bs[e][tx*4];
        acc[0][0]+=a4.x*b4.x; acc[0][1]+=a4.x*b4.y; acc[0][2]+=a4.x*b4.z; acc[0][3]+=a4.x*b4.w;
        acc[1][0]+=a4.y*b4.x; acc[1][1]+=a4.y*b4.y; acc[1][2]+=a4.y*b4.z; acc[1][3]+=a4.y*b4.w;
        acc[2][0]+=a4.z*b4.x; acc[2][1]+=a4.z*b4.y; acc[2][2]+=a4.z*b4.z; acc[2][3]+=a4.z*b4.w;
        acc[3][0]+=a4.w*b4.x; acc[3][1]+=a4.w*b4.y; acc[3][2]+=a4.w*b4.z; acc[3][3]+=a4.w*b4.w;
      }
      __syncthreads();
    }
    #pragma unroll
    for (int ii = 0; ii < 4; ++ii)
      *(float4*)(C + (size_t)(i0+ty*4+ii)*256 + j0 + tx*4) =
        make_float4(acc[ii][0], acc[ii][1], acc[ii][2], acc[ii][3]);
    return;
  }

  if (blk >= 1024){
    // ---- gh: gh[g][r][cbase..+8) = sin@W_hh[g]^T + b_hh[g]  (round-8 proven) ----
    float (*xs)[260]  = (float(*)[260])U;
    float (*wsh)[260] = (float(*)[260])(U + 4160);
    const int idx = blk - 1024;          // 0..767
    const int g = idx >> 8, sub = idx & 255;
    const int sg = sub >> 5, cgi = sub & 31, cbase = cgi * 8;
    #pragma unroll
    for (int i = 0; i < 4; ++i){
      int idx4 = tid + i*256, jj = idx4 >> 6, k4 = idx4 & 63;
      *(float4*)&xs[jj][k4*4] = *(const float4*)(sin_ + ((size_t)(sg + 8*jj))*256 + k4*4);
    }
    #pragma unroll
    for (int i = 0; i < 2; ++i){
      int idx4 = tid + i*256, row = idx4 >> 6, k4 = idx4 & 63;
      *(float4*)&wsh[row][k4*4] =
        *(const float4*)(W_hh + (size_t)g*65536 + ((size_t)(cbase + row))*256 + k4*4);
    }
    __syncthreads();
    if (tid < 128){
      const int j = tid >> 3, cc = tid & 7, r = sg + 8*j, c = cbase + cc;
      ghb[((size_t)g*128 + r)*256 + c] = dot256(&wsh[cc][0], &xs[j][0]) + b_hh[g*256 + c];
    }
    return;
  }

  // ---- attention (round-8 proven): 64-token tile, two global passes over emb ----
  float* const qgL = U;
  float* const avL = U + 2048;
  float4* const Sp4 = (float4*)U;

  const int b = blk >> 6, tile = blk & 63;
  const int n0 = tile * 64;

  {
    const float4* src = (const float4*)(qg + (size_t)b * 2048);
    float4* dst = (float4*)qgL;
    #pragma unroll
    for (int k = 0; k < 2; ++k){
      int w = tid + k*256;
      int s = w >> 6, f = w & 63, qq = f >> 3, j = f & 7;
      dst[s*64 + qq*8 + ((j + qq) & 7)] = src[w];
    }
  }
  if (tid < 8){
    GqL[tid] = gqbq[(b*8 + tid)*2 + 0];
    BqL[tid] = gqbq[(b*8 + tid)*2 + 1];
  }
  __syncthreads();

  const int qq = tid & 7;
  float zsum[8], z2sum[8];
  #pragma unroll
  for (int s = 0; s < 8; ++s){ zsum[s] = 0.f; z2sum[s] = 0.f; }

  #pragma unroll
  for (int pass = 0; pass < 2; ++pass){
    const int t = pass*32 + (tid >> 3);
    const float4* xrow = (const float4*)(emb + ((size_t)(b*4096 + n0 + t))*256 + qq*32);
    float4 xv4[8];
    #pragma unroll
    for (int j = 0; j < 8; ++j) xv4[j] = xrow[j];
    float s1 = 0.f, s2 = 0.f, acc[8];
    #pragma unroll
    for (int s = 0; s < 8; ++s) acc[s] = 0.f;
    #pragma unroll
    for (int j = 0; j < 8; ++j){
      float4 u = xv4[j];
      s1 += (u.x+u.y)+(u.z+u.w);
      s2 += u.x*u.x+u.y*u.y+u.z*u.z+u.w*u.w;
      const float* qb = qgL + qq*32 + ((j + qq) & 7)*4;
      #pragma unroll
      for (int s = 0; s < 8; ++s){
        float4 q0 = *(const float4*)(qb + s*256);
        acc[s] += u.x*q0.x + u.y*q0.y + u.z*q0.z + u.w*q0.w;
      }
    }
    #pragma unroll
    for (int o = 1; o <= 4; o <<= 1){
      s1 += __shfl_xor(s1,o,64); s2 += __shfl_xor(s2,o,64);
      #pragma unroll
      for (int s = 0; s < 8; ++s) acc[s] += __shfl_xor(acc[s],o,64);
    }
    float mu = s1 * (1.f/256.f);
    float var = s2 * (1.f/256.f) - mu*mu;
    float inv = rsqrtf(var + LN_EPS);
    float dv[8], mx = -1e30f;
    #pragma unroll
    for (int s = 0; s < 8; ++s){
      dv[s] = inv * (acc[s] - mu * GqL[s]) + BqL[s];
      mx = fmaxf(mx, dv[s]);
    }
    float den = 0.f;
    #pragma unroll
    for (int s = 0; s < 8; ++s){ dv[s] = expf(dv[s] - mx); den += dv[s]; }
    float rden = 1.f / den;
    #pragma unroll
    for (int s = 0; s < 8; ++s){
      float at = dv[s] * rden;
      float av = at * inv;
      if (qq == 0){ avL[s*64 + t] = at; aL[s*64 + t] = av; }
      zsum[s] += at;
      z2sum[s] += av * mu;
    }
  }
  #pragma unroll
  for (int s = 0; s < 8; ++s){
    #pragma unroll
    for (int o = 32; o; o >>= 1){
      zsum[s] += __shfl_xor(zsum[s], o, 64);
      z2sum[s] += __shfl_xor(z2sum[s], o, 64);
    }
  }
  if (lane == 0){
    #pragma unroll
    for (int s = 0; s < 8; ++s){ red2[0][s][wv] = zsum[s]*0.125f; red2[1][s][wv] = z2sum[s]*0.125f; }
  }
  __syncthreads();
  if (tid < 8){
    Zs[tid]  = red2[0][tid][0]+red2[0][tid][1]+red2[0][tid][2]+red2[0][tid][3];
    A2s[tid] = red2[1][tid][0]+red2[1][tid][1]+red2[1][tid][2]+red2[1][tid][3];
  }
  if (write_attn){
    int s = tid >> 5, tk = tid & 31;
    #pragma unroll
    for (int p = 0; p < 2; ++p)
      out_attn[((size_t)(b*8 + s))*4096 + n0 + p*32 + tk] = avL[s*64 + p*32 + tk];
  }
  __syncthreads();
  {
    const int r4 = tid >> 6, cq = tid & 63;
    float4 S1[8];
    #pragma unroll
    for (int s = 0; s < 8; ++s) S1[s] = make_float4(0.f,0.f,0.f,0.f);
    const float4* xbase = (const float4*)(emb + ((size_t)(b*4096 + n0))*256) + cq;
    #pragma unroll 4
    for (int i = 0; i < 16; ++i){
      int t = r4 + i*4;
      float4 x4 = xbase[t*64];
      #pragma unroll
      for (int s = 0; s < 8; ++s){
        float a = aL[s*64 + t];
        S1[s].x += a*x4.x; S1[s].y += a*x4.y; S1[s].z += a*x4.z; S1[s].w += a*x4.w;
      }
    }
    #pragma unroll
    for (int s = 0; s < 8; ++s) Sp4[(r4*8 + s)*64 + cq] = S1[s];
  }
  __syncthreads();
  {
    const int c = tid;
    const float* Sp = (const float*)Sp4;
    float gc = g_in[c], bc = be_in[c];
    float* dst = uacc + ((size_t)b*8)*256 + c;
    #pragma unroll
    for (int si = 0; si < 8; ++si){
      int s = (si + blk) & 7;
      float v = Sp[(0*8+s)*256 + c] + Sp[(1*8+s)*256 + c]
              + Sp[(2*8+s)*256 + c] + Sp[(3*8+s)*256 + c];
      atomicAdd(&dst[s*256], gc * (v - A2s[s]) + bc * Zs[s]);
    }
    if (tid < 8) atomicAdd(&Zacc[b*8 + tid], Zs[tid]);
  }
}

extern "C" void kernel_launch(void* const* d_in, const int* in_sizes, int n_in,
                              void* d_out, int out_size, void* d_ws, size_t ws_size,
                              hipStream_t stream){
  const float* emb   = (const float*)d_in[0];
  const float* noise = (const float*)d_in[1];
  const float* smu   = (const float*)d_in[2];
  const float* slsig = (const float*)d_in[3];
  const float* Wk    = (const float*)d_in[4];
  const float* Wq    = (const float*)d_in[5];
  const float* Wv    = (const float*)d_in[6];
  const float* W_ih  = (const float*)d_in[7];
  const float* W_hh  = (const float*)d_in[8];
  const float* b_ih  = (const float*)d_in[9];
  const float* b_hh  = (const float*)d_in[10];
  const float* W1    = (const float*)d_in[11];
  const float* b1    = (const float*)d_in[12];
  const float* W2    = (const float*)d_in[13];
  const float* b2    = (const float*)d_in[14];
  const float* g_in  = (const float*)d_in[15];
  const float* be_in = (const float*)d_in[16];
  const float* g_s   = (const float*)d_in[17];
  const float* be_s  = (const float*)d_in[18];
  const float* g_ff  = (const float*)d_in[19];
  const float* be_ff = (const float*)d_in[20];

  float* ws     = (float*)d_ws;
  float* slotsA = ws;                 // 32768
  float* slotsB = ws + 32768;         // 32768
  float* qg     = ws + 65536;         // 32768
  float* gqbq   = ws + 98304;         // 256
  float* uacc   = ws + 98560;         // 32768
  float* Zacc   = ws + 131328;        // 128
  float* ghb    = ws + 131456;        // 98304
  float* hbuf   = ws + 229760;        // 32768
  float* hid    = ws + 262528;        // 32768
  float* Wf     = ws + 295296;        // 1572864 (6 MB)
  float* Mt     = ws + 1868160;       // 524288  (2 MB)

  float* out_slots = (float*)d_out;
  float* out_attn  = out_slots + 32768;
  const int has_attn = (out_size >= 32768 + 16*8*4096);

  k_initq<<<dim3(128), dim3(256), 0, stream>>>(noise, smu, slsig, slotsA, uacc, Zacc,
      g_s, be_s, Wq, Wk, g_in, be_in, qg, gqbq);
  for (int it = 0; it < 3; ++it){
    int last = (it == 2);
    float* sin  = (it == 1) ? slotsB : slotsA;
    float* sout = (it == 1) ? slotsA : slotsB;
    int grid = (it == 0) ? 2304 : 1792;   // it0 carries the Wf/Mt precompute blocks
    k_main_gh<<<dim3(grid), dim3(256), 0, stream>>>(emb, qg, gqbq, g_in, be_in,
        uacc, Zacc, out_attn, last && has_attn, sin, W_hh, b_hh, ghb,
        W_ih, Wv, Wk, Wq, Wf, Mt);
    k_gruF<<<dim3(256), dim3(256), 0, stream>>>(sin, uacc, Zacc, Wf, b_ih, ghb, hbuf);
    k_ffa<<<dim3(256), dim3(256), 0, stream>>>(hbuf, g_ff, be_ff, W1, b1, hid, uacc, Zacc);
    k_ffb<<<dim3(256), dim3(256), 0, stream>>>(hid, hbuf, W2, b2, sout, out_slots,
        gqbq, last);
    if (!last)
      k_lnqk<<<dim3(256), dim3(256), 0, stream>>>(sout, g_s, be_s, Mt, g_in, be_in,
          qg, gqbq);
  }
}

// Round 11
// 322.185 us; speedup vs baseline: 1.1233x; 1.0146x over previous
//
#include <hip/hip_runtime.h>

#define DEVI __device__ __forceinline__

constexpr float SCALE = 0.0625f;   // 256^-0.5
constexpr float LN_EPS = 1e-5f;

DEVI float dot256(const float* w, const float* x){
  float4 A = make_float4(0.f,0.f,0.f,0.f);
  #pragma unroll 8
  for (int k = 0; k < 64; ++k){
    float4 w4 = *(const float4*)(w + k*4);
    float4 x4 = *(const float4*)(x + k*4);
    A.x += w4.x*x4.x; A.y += w4.y*x4.y; A.z += w4.z*x4.z; A.w += w4.w*x4.w;
  }
  return (A.x+A.y)+(A.z+A.w);
}

// ---------- helpers for the once-only initq path (proven rounds 4-10) ----------
DEVI float gemv_row(const float* __restrict__ W, const float4* __restrict__ xv4, int tid){
  const float4* wr = (const float4*)(W + (size_t)tid*256);
  float a0=0.f, a1=0.f, a2=0.f, a3=0.f;
  #pragma unroll 16
  for (int k = 0; k < 64; ++k){
    float4 w = wr[k];
    float4 x = xv4[k];
    a0 += w.x*x.x; a1 += w.y*x.y; a2 += w.z*x.z; a3 += w.w*x.w;
  }
  return (a0+a1)+(a2+a3);
}

DEVI float gemv_col(const float* __restrict__ W, const float4* __restrict__ xv4, int tid){
  const float* wc = W + tid;
  float a0=0.f, a1=0.f, a2=0.f, a3=0.f;
  #pragma unroll 8
  for (int e4 = 0; e4 < 64; ++e4){
    float4 x = xv4[e4];
    const float* p = wc + (size_t)e4*1024;
    a0 += x.x*p[0]; a1 += x.y*p[256]; a2 += x.z*p[512]; a3 += x.w*p[768];
  }
  return (a0+a1)+(a2+a3);
}

DEVI float block_ln(float x, const float* __restrict__ g, const float* __restrict__ be,
                    float* red, int tid, int lane, int wv){
  float v1 = x, v2 = x*x;
  #pragma unroll
  for (int o = 32; o; o >>= 1){ v1 += __shfl_xor(v1,o,64); v2 += __shfl_xor(v2,o,64); }
  if (lane == 0){ red[wv] = v1; red[4+wv] = v2; }
  __syncthreads();
  float mu = (red[0]+red[1]+red[2]+red[3]) * (1.f/256.f);
  float var = (red[4]+red[5]+red[6]+red[7]) * (1.f/256.f) - mu*mu;
  float inv = rsqrtf(var + LN_EPS);
  float r = (x - mu)*inv*g[tid] + be[tid];
  __syncthreads();
  return r;
}

// ---------------- kInitQ: slots init + zero accumulators + q-projection (once) ---------
__global__ __launch_bounds__(256) void k_initq(const float* __restrict__ noise,
    const float* __restrict__ smu, const float* __restrict__ slsig,
    float* __restrict__ slotsA, float* __restrict__ uacc, float* __restrict__ Zacc,
    const float* __restrict__ g_s, const float* __restrict__ be_s,
    const float* __restrict__ Wq, const float* __restrict__ Wk,
    const float* __restrict__ g_in, const float* __restrict__ be_in,
    float* __restrict__ qg, float* __restrict__ gqbq){
  __shared__ float4 xv4[64];
  __shared__ float red[8];
  float* xv = (float*)xv4;
  const int r = blockIdx.x, tid = threadIdx.x, s = r & 7;
  const int lane = tid & 63, wv = tid >> 6;
  float sl = smu[s*256 + tid] + expf(slsig[s*256 + tid]) * noise[r*256 + tid];
  slotsA[r*256 + tid] = sl;
  uacc[r*256 + tid] = 0.f;
  if (tid == 0) Zacc[r] = 0.f;
  float sn = block_ln(sl, g_s, be_s, red, tid, lane, wv);
  xv[tid] = sn;
  __syncthreads();
  float q = gemv_row(Wq, xv4, tid);
  __syncthreads();
  xv[tid] = q;
  __syncthreads();
  float qk = gemv_col(Wk + (size_t)s*65536, xv4, tid);
  float qgv = qk * g_in[tid] * SCALE;
  float bqv = qk * be_in[tid] * SCALE;
  qg[r*256 + tid] = qgv;
  float vq = qgv, vb = bqv;
  #pragma unroll
  for (int o = 32; o; o >>= 1){ vq += __shfl_xor(vq,o,64); vb += __shfl_xor(vb,o,64); }
  if (lane == 0){ red[wv] = vq; red[4+wv] = vb; }
  __syncthreads();
  if (tid == 0) gqbq[r*2+0] = red[0]+red[1]+red[2]+red[3];
  if (tid == 1) gqbq[r*2+1] = red[4]+red[5]+red[6]+red[7];
}

// ===== tiled stages (proven round 8): 256 blocks = 8 sg x 32 col-groups of 8 =====

__global__ __launch_bounds__(256) void k_gruF(const float* __restrict__ sin_,
    const float* __restrict__ uacc, const float* __restrict__ Zacc,
    const float* __restrict__ Wf, const float* __restrict__ b_ih,
    const float* __restrict__ ghb, float* __restrict__ hbuf){
  __shared__ float xs[16][260];
  __shared__ float ws[24][260];
  const int tid = threadIdx.x, bid = blockIdx.x;
  const int sg = bid >> 5, cgi = bid & 31, cbase = cgi * 8;
  #pragma unroll
  for (int i = 0; i < 4; ++i){
    int idx4 = tid + i*256, jj = idx4 >> 6, k4 = idx4 & 63;
    *(float4*)&xs[jj][k4*4] = *(const float4*)(uacc + ((size_t)(sg + 8*jj))*256 + k4*4);
  }
  #pragma unroll
  for (int i = 0; i < 6; ++i){
    int idx4 = tid + i*256, row = idx4 >> 6, k4 = idx4 & 63;
    int g = row >> 3, rr = row & 7;
    *(float4*)&ws[row][k4*4] =
      *(const float4*)(Wf + (size_t)(sg*3 + g)*65536 + ((size_t)(cbase + rr))*256 + k4*4);
  }
  __syncthreads();
  if (tid < 128){
    const int j = tid >> 3, cc = tid & 7, r = sg + 8*j, c = cbase + cc;
    float rZ = 1.f / Zacc[r];
    float ir_ = dot256(&ws[cc][0],    &xs[j][0]) * rZ + b_ih[c];
    float iz_ = dot256(&ws[8+cc][0],  &xs[j][0]) * rZ + b_ih[256 + c];
    float in_ = dot256(&ws[16+cc][0], &xs[j][0]) * rZ + b_ih[512 + c];
    float hr_ = ghb[((size_t)0*128 + r)*256 + c];
    float hz_ = ghb[((size_t)1*128 + r)*256 + c];
    float hn_ = ghb[((size_t)2*128 + r)*256 + c];
    float hp  = sin_[(size_t)r*256 + c];
    float rg = 1.f/(1.f + expf(-(ir_ + hr_)));
    float zg = 1.f/(1.f + expf(-(iz_ + hz_)));
    float ng = tanhf(in_ + rg*hn_);
    hbuf[(size_t)r*256 + c] = (1.f - zg)*ng + zg*hp;
  }
}

__global__ __launch_bounds__(256) void k_ffa(const float* __restrict__ hbuf,
    const float* __restrict__ g_ff, const float* __restrict__ be_ff,
    const float* __restrict__ W1, const float* __restrict__ b1,
    float* __restrict__ hid, float* __restrict__ uacc, float* __restrict__ Zacc){
  __shared__ float xs[16][260];
  __shared__ float ws[8][260];
  __shared__ float gA[256], gB[256];
  __shared__ float redA[16][17], redB[16][17];
  __shared__ float musL[16], invsL[16];
  const int tid = threadIdx.x, bid = blockIdx.x;
  const int sg = bid >> 5, cgi = bid & 31, cbase = cgi * 8;
  #pragma unroll
  for (int i = 0; i < 4; ++i){
    int idx4 = tid + i*256, jj = idx4 >> 6, k4 = idx4 & 63;
    *(float4*)&xs[jj][k4*4] = *(const float4*)(hbuf + ((size_t)(sg + 8*jj))*256 + k4*4);
  }
  #pragma unroll
  for (int i = 0; i < 2; ++i){
    int idx4 = tid + i*256, row = idx4 >> 6, k4 = idx4 & 63;
    *(float4*)&ws[row][k4*4] = *(const float4*)(W1 + ((size_t)(cbase + row))*256 + k4*4);
  }
  gA[tid] = g_ff[tid]; gB[tid] = be_ff[tid];
  __syncthreads();
  {
    int jr = tid >> 4, seg = tid & 15;
    float s1 = 0.f, s2 = 0.f;
    #pragma unroll
    for (int i = 0; i < 16; ++i){ float v = xs[jr][seg*16 + i]; s1 += v; s2 += v*v; }
    redA[jr][seg] = s1; redB[jr][seg] = s2;
    __syncthreads();
    if (tid < 16){
      float t1 = 0.f, t2 = 0.f;
      #pragma unroll
      for (int p = 0; p < 16; ++p){ t1 += redA[tid][p]; t2 += redB[tid][p]; }
      float mu = t1 * (1.f/256.f);
      float var = t2 * (1.f/256.f) - mu*mu;
      musL[tid] = mu; invsL[tid] = rsqrtf(var + LN_EPS);
    }
    __syncthreads();
    float mu = musL[jr], inv = invsL[jr];
    #pragma unroll
    for (int i = 0; i < 16; ++i){
      int k = seg*16 + i;
      xs[jr][k] = (xs[jr][k] - mu)*inv*gA[k] + gB[k];
    }
  }
  __syncthreads();
  if (tid < 128){
    const int j = tid >> 3, cc = tid & 7, r = sg + 8*j, c = cbase + cc;
    hid[(size_t)r*256 + c] = fmaxf(dot256(&ws[cc][0], &xs[j][0]) + b1[c], 0.f);
    uacc[(size_t)r*256 + c] = 0.f;
  }
  if (cgi == 0 && tid < 16) Zacc[sg + 8*tid] = 0.f;
}

__global__ __launch_bounds__(256) void k_ffb(const float* __restrict__ hid,
    const float* __restrict__ hbuf, const float* __restrict__ W2,
    const float* __restrict__ b2, float* __restrict__ sout,
    float* __restrict__ out_slots, float* __restrict__ gqbq, int last){
  __shared__ float xs[16][260];
  __shared__ float ws[8][260];
  const int tid = threadIdx.x, bid = blockIdx.x;
  const int sg = bid >> 5, cgi = bid & 31, cbase = cgi * 8;
  #pragma unroll
  for (int i = 0; i < 4; ++i){
    int idx4 = tid + i*256, jj = idx4 >> 6, k4 = idx4 & 63;
    *(float4*)&xs[jj][k4*4] = *(const float4*)(hid + ((size_t)(sg + 8*jj))*256 + k4*4);
  }
  #pragma unroll
  for (int i = 0; i < 2; ++i){
    int idx4 = tid + i*256, row = idx4 >> 6, k4 = idx4 & 63;
    *(float4*)&ws[row][k4*4] = *(const float4*)(W2 + ((size_t)(cbase + row))*256 + k4*4);
  }
  __syncthreads();
  if (tid < 128){
    const int j = tid >> 3, cc = tid & 7, r = sg + 8*j, c = cbase + cc;
    float out = hbuf[(size_t)r*256 + c] + dot256(&ws[cc][0], &xs[j][0]) + b2[c];
    sout[(size_t)r*256 + c] = out;
    if (last) out_slots[(size_t)r*256 + c] = out;
  }
  if (cgi == 0 && tid < 32)
    gqbq[(sg + 8*(tid>>1))*2 + (tid&1)] = 0.f;
}

__global__ __launch_bounds__(256) void k_lnqk(const float* __restrict__ sl,
    const float* __restrict__ g_s, const float* __restrict__ be_s,
    const float* __restrict__ Mt,
    const float* __restrict__ g_in, const float* __restrict__ be_in,
    float* __restrict__ qg, float* __restrict__ gqbq){
  __shared__ float xs[16][260];
  __shared__ float ws[8][260];
  __shared__ float gA[256], gB[256];
  __shared__ float redA[16][17], redB[16][17];
  __shared__ float musL[16], invsL[16];
  const int tid = threadIdx.x, bid = blockIdx.x;
  const int sg = bid >> 5, cgi = bid & 31, cbase = cgi * 8;
  #pragma unroll
  for (int i = 0; i < 4; ++i){
    int idx4 = tid + i*256, jj = idx4 >> 6, k4 = idx4 & 63;
    *(float4*)&xs[jj][k4*4] = *(const float4*)(sl + ((size_t)(sg + 8*jj))*256 + k4*4);
  }
  #pragma unroll
  for (int i = 0; i < 2; ++i){
    int idx4 = tid + i*256, row = idx4 >> 6, k4 = idx4 & 63;
    *(float4*)&ws[row][k4*4] =
      *(const float4*)(Mt + (size_t)sg*65536 + ((size_t)(cbase + row))*256 + k4*4);
  }
  gA[tid] = g_s[tid]; gB[tid] = be_s[tid];
  __syncthreads();
  {
    int jr = tid >> 4, seg = tid & 15;
    float s1 = 0.f, s2 = 0.f;
    #pragma unroll
    for (int i = 0; i < 16; ++i){ float v = xs[jr][seg*16 + i]; s1 += v; s2 += v*v; }
    redA[jr][seg] = s1; redB[jr][seg] = s2;
    __syncthreads();
    if (tid < 16){
      float t1 = 0.f, t2 = 0.f;
      #pragma unroll
      for (int p = 0; p < 16; ++p){ t1 += redA[tid][p]; t2 += redB[tid][p]; }
      float mu = t1 * (1.f/256.f);
      float var = t2 * (1.f/256.f) - mu*mu;
      musL[tid] = mu; invsL[tid] = rsqrtf(var + LN_EPS);
    }
    __syncthreads();
    float mu = musL[jr], inv = invsL[jr];
    #pragma unroll
    for (int i = 0; i < 16; ++i){
      int k = seg*16 + i;
      xs[jr][k] = (xs[jr][k] - mu)*inv*gA[k] + gB[k];
    }
  }
  __syncthreads();
  if (tid < 128){
    const int j = tid >> 3, cc = tid & 7, r = sg + 8*j, c = cbase + cc;
    float qk = dot256(&ws[cc][0], &xs[j][0]);
    float qgv = qk * g_in[c] * SCALE;
    float bqv = qk * be_in[c] * SCALE;
    qg[(size_t)r*256 + c] = qgv;
    float vq = qgv, vb = bqv;
    #pragma unroll
    for (int o = 1; o <= 4; o <<= 1){ vq += __shfl_xor(vq,o,64); vb += __shfl_xor(vb,o,64); }
    if (cc == 0){
      atomicAdd(&gqbq[r*2+0], vq);
      atomicAdd(&gqbq[r*2+1], vb);
    }
  }
}

// ---------------- K1: attn blocks 0..1023 (64-token tiles, slim LDS)
//                  + gh blocks 1024..2559 (8-row) + (it0) Wf/Mt GEMM 2560..3071 ----------
__global__ __launch_bounds__(256) void k_main_gh(const float* __restrict__ emb,
    const float* __restrict__ qg, const float* __restrict__ gqbq,
    const float* __restrict__ g_in, const float* __restrict__ be_in,
    float* __restrict__ uacc, float* __restrict__ Zacc,
    float* __restrict__ out_attn, int write_attn,
    const float* __restrict__ sin_, const float* __restrict__ W_hh,
    const float* __restrict__ b_hh, float* __restrict__ ghb,
    const float* __restrict__ W_ih, const float* __restrict__ Wv,
    const float* __restrict__ Wk, const float* __restrict__ Wq,
    float* __restrict__ Wf, float* __restrict__ Mt){
  __shared__ float U[4352];                    // 17 KB union
  __shared__ float aL[512];
  __shared__ float red2[2][8][4];
  __shared__ float Zs[8], A2s[8], GqL[8], BqL[8];

  const int tid = threadIdx.x, lane = tid & 63, wv = tid >> 6;
  const int blk = blockIdx.x;

  if (blk >= 2560){
    // ---- Wf/Mt GEMM (it0 only): 64x64 tile, K-slice 32 (At[32][68]+Bs[32][68]) ----
    float (*At)[68] = (float(*)[68])U;             // [32][68]
    float (*Bs)[68] = (float(*)[68])(U + 2176);    // [32][68]
    const int gb = blk - 2560;
    const bool isWf = gb < 384;
    const float *A, *B; float *C;
    int tile;
    if (isWf){
      int gm = gb >> 4; tile = gb & 15;        // gm = s*3+g
      A = W_ih + (size_t)(gm % 3) * 65536;     // [i][e] -> transpose load
      B = Wv   + (size_t)(gm / 3) * 65536;     // [e][j]
      C = Wf   + (size_t)gm * 65536;
    } else {
      int gm = (gb - 384) >> 4; tile = (gb - 384) & 15;
      A = Wk + (size_t)gm * 65536;             // [e][c]
      B = Wq;                                  // [e][d]
      C = Mt + (size_t)gm * 65536;
    }
    const int i0 = (tile >> 2) * 64, j0 = (tile & 3) * 64;
    const int ty = tid >> 4, tx = tid & 15;
    float acc[4][4];
    #pragma unroll
    for (int a = 0; a < 4; ++a)
      #pragma unroll
      for (int b = 0; b < 4; ++b) acc[a][b] = 0.f;
    for (int ko = 0; ko < 256; ko += 32){
      #pragma unroll
      for (int p = 0; p < 2; ++p){
        int idx4 = tid + p*256;
        int e = idx4 >> 4, jl4 = idx4 & 15;
        *(float4*)&Bs[e][jl4*4] = *(const float4*)(B + (size_t)(ko+e)*256 + j0 + jl4*4);
      }
      if (isWf){
        #pragma unroll
        for (int p = 0; p < 2; ++p){
          int idx4 = tid + p*256;
          int il = idx4 >> 3, e4 = idx4 & 7;
          float4 w = *(const float4*)(A + (size_t)(i0+il)*256 + ko + e4*4);
          At[e4*4+0][il] = w.x; At[e4*4+1][il] = w.y;
          At[e4*4+2][il] = w.z; At[e4*4+3][il] = w.w;
        }
      } else {
        #pragma unroll
        for (int p = 0; p < 2; ++p){
          int idx4 = tid + p*256;
          int e = idx4 >> 4, il4 = idx4 & 15;
          *(float4*)&At[e][il4*4] = *(const float4*)(A + (size_t)(ko+e)*256 + i0 + il4*4);
        }
      }
      __syncthreads();
      #pragma unroll 4
      for (int e = 0; e < 32; ++e){
        float4 a4 = *(const float4*)&At[e][ty*4];
        float4 b4 = *(const float4*)&Bs[e][tx*4];
        acc[0][0]+=a4.x*b4.x; acc[0][1]+=a4.x*b4.y; acc[0][2]+=a4.x*b4.z; acc[0][3]+=a4.x*b4.w;
        acc[1][0]+=a4.y*b4.x; acc[1][1]+=a4.y*b4.y; acc[1][2]+=a4.y*b4.z; acc[1][3]+=a4.y*b4.w;
        acc[2][0]+=a4.z*b4.x; acc[2][1]+=a4.z*b4.y; acc[2][2]+=a4.z*b4.z; acc[2][3]+=a4.z*b4.w;
        acc[3][0]+=a4.w*b4.x; acc[3][1]+=a4.w*b4.y; acc[3][2]+=a4.w*b4.z; acc[3][3]+=a4.w*b4.w;
      }
      __syncthreads();
    }
    #pragma unroll
    for (int ii = 0; ii < 4; ++ii)
      *(float4*)(C + (size_t)(i0+ty*4+ii)*256 + j0 + tx*4) =
        make_float4(acc[ii][0], acc[ii][1], acc[ii][2], acc[ii][3]);
    return;
  }

  if (blk >= 1024){
    // ---- gh (8-row blocks): gh[g][r][cbase..+8) = sin@W_hh[g]^T + b_hh[g] ----
    float (*xs)[260]  = (float(*)[260])U;          // [8][260]
    float (*wsh)[260] = (float(*)[260])(U + 2080); // [8][260]
    const int idx = blk - 1024;          // 0..1535
    const int g = idx >> 9, sub = idx & 511;
    const int sg = sub >> 6, rest = sub & 63, rh = rest >> 5, cgi = rest & 31;
    const int cbase = cgi * 8;
    #pragma unroll
    for (int i = 0; i < 2; ++i){
      int idx4 = tid + i*256, jj = idx4 >> 6, k4 = idx4 & 63;
      *(float4*)&xs[jj][k4*4] =
        *(const float4*)(sin_ + ((size_t)(sg + 8*(rh*8 + jj)))*256 + k4*4);
    }
    #pragma unroll
    for (int i = 0; i < 2; ++i){
      int idx4 = tid + i*256, row = idx4 >> 6, k4 = idx4 & 63;
      *(float4*)&wsh[row][k4*4] =
        *(const float4*)(W_hh + (size_t)g*65536 + ((size_t)(cbase + row))*256 + k4*4);
    }
    __syncthreads();
    if (tid < 64){
      const int j = tid >> 3, cc = tid & 7;
      const int r = sg + 8*(rh*8 + j), c = cbase + cc;
      ghb[((size_t)g*128 + r)*256 + c] = dot256(&wsh[cc][0], &xs[j][0]) + b_hh[g*256 + c];
    }
    return;
  }

  // ---- attention: 64-token tile, slim-LDS phase 2 (2 partial groups) ----
  float* const qgL = U;                        // [2048] phase 1 (bank-swizzled)
  float* const avL = U + 2048;                 // [512]  phase 1
  float4* const Sp4 = (float4*)U;              // [1024] float4 phase 2 (overlays)

  const int b = blk >> 6, tile = blk & 63;
  const int n0 = tile * 64;

  {
    const float4* src = (const float4*)(qg + (size_t)b * 2048);
    float4* dst = (float4*)qgL;
    #pragma unroll
    for (int k = 0; k < 2; ++k){
      int w = tid + k*256;
      int s = w >> 6, f = w & 63, qq = f >> 3, j = f & 7;
      dst[s*64 + qq*8 + ((j + qq) & 7)] = src[w];
    }
  }
  if (tid < 8){
    GqL[tid] = gqbq[(b*8 + tid)*2 + 0];
    BqL[tid] = gqbq[(b*8 + tid)*2 + 1];
  }
  __syncthreads();

  const int qq = tid & 7;
  float zsum[8], z2sum[8];
  #pragma unroll
  for (int s = 0; s < 8; ++s){ zsum[s] = 0.f; z2sum[s] = 0.f; }

  #pragma unroll
  for (int pass = 0; pass < 2; ++pass){
    const int t = pass*32 + (tid >> 3);
    const float4* xrow = (const float4*)(emb + ((size_t)(b*4096 + n0 + t))*256 + qq*32);
    float4 xv4[8];
    #pragma unroll
    for (int j = 0; j < 8; ++j) xv4[j] = xrow[j];
    float s1 = 0.f, s2 = 0.f, acc[8];
    #pragma unroll
    for (int s = 0; s < 8; ++s) acc[s] = 0.f;
    #pragma unroll
    for (int j = 0; j < 8; ++j){
      float4 u = xv4[j];
      s1 += (u.x+u.y)+(u.z+u.w);
      s2 += u.x*u.x+u.y*u.y+u.z*u.z+u.w*u.w;
      const float* qb = qgL + qq*32 + ((j + qq) & 7)*4;
      #pragma unroll
      for (int s = 0; s < 8; ++s){
        float4 q0 = *(const float4*)(qb + s*256);
        acc[s] += u.x*q0.x + u.y*q0.y + u.z*q0.z + u.w*q0.w;
      }
    }
    #pragma unroll
    for (int o = 1; o <= 4; o <<= 1){
      s1 += __shfl_xor(s1,o,64); s2 += __shfl_xor(s2,o,64);
      #pragma unroll
      for (int s = 0; s < 8; ++s) acc[s] += __shfl_xor(acc[s],o,64);
    }
    float mu = s1 * (1.f/256.f);
    float var = s2 * (1.f/256.f) - mu*mu;
    float inv = rsqrtf(var + LN_EPS);
    float dv[8], mx = -1e30f;
    #pragma unroll
    for (int s = 0; s < 8; ++s){
      dv[s] = inv * (acc[s] - mu * GqL[s]) + BqL[s];
      mx = fmaxf(mx, dv[s]);
    }
    float den = 0.f;
    #pragma unroll
    for (int s = 0; s < 8; ++s){ dv[s] = expf(dv[s] - mx); den += dv[s]; }
    float rden = 1.f / den;
    #pragma unroll
    for (int s = 0; s < 8; ++s){
      float at = dv[s] * rden;
      float av = at * inv;
      if (qq == 0){ avL[s*64 + t] = at; aL[s*64 + t] = av; }
      zsum[s] += at;
      z2sum[s] += av * mu;
    }
  }
  #pragma unroll
  for (int s = 0; s < 8; ++s){
    #pragma unroll
    for (int o = 32; o; o >>= 1){
      zsum[s] += __shfl_xor(zsum[s], o, 64);
      z2sum[s] += __shfl_xor(z2sum[s], o, 64);
    }
  }
  if (lane == 0){
    #pragma unroll
    for (int s = 0; s < 8; ++s){ red2[0][s][wv] = zsum[s]*0.125f; red2[1][s][wv] = z2sum[s]*0.125f; }
  }
  __syncthreads();
  if (tid < 8){
    Zs[tid]  = red2[0][tid][0]+red2[0][tid][1]+red2[0][tid][2]+red2[0][tid][3];
    A2s[tid] = red2[1][tid][0]+red2[1][tid][1]+red2[1][tid][2]+red2[1][tid][3];
  }
  if (write_attn){
    int s = tid >> 5, tk = tid & 31;
    #pragma unroll
    for (int p = 0; p < 2; ++p)
      out_attn[((size_t)(b*8 + s))*4096 + n0 + p*32 + tk] = avL[s*64 + p*32 + tk];
  }
  __syncthreads();                   // avL/qgL dead past here; Sp4 takes over
  { // phase 2: 2 row-groups x 2 slot-halves; 32 tokens x 4 slots each
    const int r2 = tid >> 7, sh = (tid >> 6) & 1, cq = tid & 63;
    float4 S1[4];
    #pragma unroll
    for (int so = 0; so < 4; ++so) S1[so] = make_float4(0.f,0.f,0.f,0.f);
    const float4* xbase = (const float4*)(emb + ((size_t)(b*4096 + n0))*256) + cq;
    #pragma unroll 4
    for (int i = 0; i < 32; ++i){
      int t = r2 + i*2;
      float4 x4 = xbase[t*64];
      #pragma unroll
      for (int so = 0; so < 4; ++so){
        float a = aL[(sh*4+so)*64 + t];   // wave-uniform broadcast
        S1[so].x += a*x4.x; S1[so].y += a*x4.y; S1[so].z += a*x4.z; S1[so].w += a*x4.w;
      }
    }
    #pragma unroll
    for (int so = 0; so < 4; ++so) Sp4[(r2*8 + sh*4+so)*64 + cq] = S1[so];
  }
  __syncthreads();
  { // final: sum 2 partials per (s,c), atomically accumulate (s staggered)
    const int c = tid;
    const float* Sp = (const float*)Sp4;
    float gc = g_in[c], bc = be_in[c];
    float* dst = uacc + ((size_t)b*8)*256 + c;
    #pragma unroll
    for (int si = 0; si < 8; ++si){
      int s = (si + blk) & 7;
      float v = Sp[(0*8+s)*256 + c] + Sp[(1*8+s)*256 + c];
      atomicAdd(&dst[s*256], gc * (v - A2s[s]) + bc * Zs[s]);
    }
    if (tid < 8) atomicAdd(&Zacc[b*8 + tid], Zs[tid]);
  }
}

extern "C" void kernel_launch(void* const* d_in, const int* in_sizes, int n_in,
                              void* d_out, int out_size, void* d_ws, size_t ws_size,
                              hipStream_t stream){
  const float* emb   = (const float*)d_in[0];
  const float* noise = (const float*)d_in[1];
  const float* smu   = (const float*)d_in[2];
  const float* slsig = (const float*)d_in[3];
  const float* Wk    = (const float*)d_in[4];
  const float* Wq    = (const float*)d_in[5];
  const float* Wv    = (const float*)d_in[6];
  const float* W_ih  = (const float*)d_in[7];
  const float* W_hh  = (const float*)d_in[8];
  const float* b_ih  = (const float*)d_in[9];
  const float* b_hh  = (const float*)d_in[10];
  const float* W1    = (const float*)d_in[11];
  const float* b1    = (const float*)d_in[12];
  const float* W2    = (const float*)d_in[13];
  const float* b2    = (const float*)d_in[14];
  const float* g_in  = (const float*)d_in[15];
  const float* be_in = (const float*)d_in[16];
  const float* g_s   = (const float*)d_in[17];
  const float* be_s  = (const float*)d_in[18];
  const float* g_ff  = (const float*)d_in[19];
  const float* be_ff = (const float*)d_in[20];

  float* ws     = (float*)d_ws;
  float* slotsA = ws;                 // 32768
  float* slotsB = ws + 32768;         // 32768
  float* qg     = ws + 65536;         // 32768
  float* gqbq   = ws + 98304;         // 256
  float* uacc   = ws + 98560;         // 32768
  float* Zacc   = ws + 131328;        // 128
  float* ghb    = ws + 131456;        // 98304
  float* hbuf   = ws + 229760;        // 32768
  float* hid    = ws + 262528;        // 32768
  float* Wf     = ws + 295296;        // 1572864 (6 MB)
  float* Mt     = ws + 1868160;       // 524288  (2 MB)

  float* out_slots = (float*)d_out;
  float* out_attn  = out_slots + 32768;
  const int has_attn = (out_size >= 32768 + 16*8*4096);

  k_initq<<<dim3(128), dim3(256), 0, stream>>>(noise, smu, slsig, slotsA, uacc, Zacc,
      g_s, be_s, Wq, Wk, g_in, be_in, qg, gqbq);
  for (int it = 0; it < 3; ++it){
    int last = (it == 2);
    float* sin  = (it == 1) ? slotsB : slotsA;
    float* sout = (it == 1) ? slotsA : slotsB;
    int grid = (it == 0) ? 3072 : 2560;   // it0 carries the Wf/Mt precompute blocks
    k_main_gh<<<dim3(grid), dim3(256), 0, stream>>>(emb, qg, gqbq, g_in, be_in,
        uacc, Zacc, out_attn, last && has_attn, sin, W_hh, b_hh, ghb,
        W_ih, Wv, Wk, Wq, Wf, Mt);
    k_gruF<<<dim3(256), dim3(256), 0, stream>>>(sin, uacc, Zacc, Wf, b_ih, ghb, hbuf);
    k_ffa<<<dim3(256), dim3(256), 0, stream>>>(hbuf, g_ff, be_ff, W1, b1, hid, uacc, Zacc);
    k_ffb<<<dim3(256), dim3(256), 0, stream>>>(hid, hbuf, W2, b2, sout, out_slots,
        gqbq, last);
    if (!last)
      k_lnqk<<<dim3(256), dim3(256), 0, stream>>>(sout, g_s, be_s, Mt, g_in, be_in,
          qg, gqbq);
  }
}

// Round 12
// 320.946 us; speedup vs baseline: 1.1277x; 1.0039x over previous
//
#include <hip/hip_runtime.h>

#define DEVI __device__ __forceinline__

constexpr float SCALE = 0.0625f;   // 256^-0.5
constexpr float LN_EPS = 1e-5f;

DEVI float dot256(const float* w, const float* x){
  float4 A = make_float4(0.f,0.f,0.f,0.f);
  #pragma unroll 8
  for (int k = 0; k < 64; ++k){
    float4 w4 = *(const float4*)(w + k*4);
    float4 x4 = *(const float4*)(x + k*4);
    A.x += w4.x*x4.x; A.y += w4.y*x4.y; A.z += w4.z*x4.z; A.w += w4.w*x4.w;
  }
  return (A.x+A.y)+(A.z+A.w);
}

// ---------- helpers for the once-only initq path (proven rounds 4-11) ----------
DEVI float gemv_row(const float* __restrict__ W, const float4* __restrict__ xv4, int tid){
  const float4* wr = (const float4*)(W + (size_t)tid*256);
  float a0=0.f, a1=0.f, a2=0.f, a3=0.f;
  #pragma unroll 16
  for (int k = 0; k < 64; ++k){
    float4 w = wr[k];
    float4 x = xv4[k];
    a0 += w.x*x.x; a1 += w.y*x.y; a2 += w.z*x.z; a3 += w.w*x.w;
  }
  return (a0+a1)+(a2+a3);
}

DEVI float gemv_col(const float* __restrict__ W, const float4* __restrict__ xv4, int tid){
  const float* wc = W + tid;
  float a0=0.f, a1=0.f, a2=0.f, a3=0.f;
  #pragma unroll 8
  for (int e4 = 0; e4 < 64; ++e4){
    float4 x = xv4[e4];
    const float* p = wc + (size_t)e4*1024;
    a0 += x.x*p[0]; a1 += x.y*p[256]; a2 += x.z*p[512]; a3 += x.w*p[768];
  }
  return (a0+a1)+(a2+a3);
}

DEVI float block_ln(float x, const float* __restrict__ g, const float* __restrict__ be,
                    float* red, int tid, int lane, int wv){
  float v1 = x, v2 = x*x;
  #pragma unroll
  for (int o = 32; o; o >>= 1){ v1 += __shfl_xor(v1,o,64); v2 += __shfl_xor(v2,o,64); }
  if (lane == 0){ red[wv] = v1; red[4+wv] = v2; }
  __syncthreads();
  float mu = (red[0]+red[1]+red[2]+red[3]) * (1.f/256.f);
  float var = (red[4]+red[5]+red[6]+red[7]) * (1.f/256.f) - mu*mu;
  float inv = rsqrtf(var + LN_EPS);
  float r = (x - mu)*inv*g[tid] + be[tid];
  __syncthreads();
  return r;
}

// ---------------- kInitQ: slots init + zero accumulators + q-projection (once) ---------
__global__ __launch_bounds__(256) void k_initq(const float* __restrict__ noise,
    const float* __restrict__ smu, const float* __restrict__ slsig,
    float* __restrict__ slotsA, float* __restrict__ uacc, float* __restrict__ Zacc,
    const float* __restrict__ g_s, const float* __restrict__ be_s,
    const float* __restrict__ Wq, const float* __restrict__ Wk,
    const float* __restrict__ g_in, const float* __restrict__ be_in,
    float* __restrict__ qg, float* __restrict__ gqbq){
  __shared__ float4 xv4[64];
  __shared__ float red[8];
  float* xv = (float*)xv4;
  const int r = blockIdx.x, tid = threadIdx.x, s = r & 7;
  const int lane = tid & 63, wv = tid >> 6;
  float sl = smu[s*256 + tid] + expf(slsig[s*256 + tid]) * noise[r*256 + tid];
  slotsA[r*256 + tid] = sl;
  uacc[r*256 + tid] = 0.f;
  if (tid == 0) Zacc[r] = 0.f;
  float sn = block_ln(sl, g_s, be_s, red, tid, lane, wv);
  xv[tid] = sn;
  __syncthreads();
  float q = gemv_row(Wq, xv4, tid);
  __syncthreads();
  xv[tid] = q;
  __syncthreads();
  float qk = gemv_col(Wk + (size_t)s*65536, xv4, tid);
  float qgv = qk * g_in[tid] * SCALE;
  float bqv = qk * be_in[tid] * SCALE;
  qg[r*256 + tid] = qgv;
  float vq = qgv, vb = bqv;
  #pragma unroll
  for (int o = 32; o; o >>= 1){ vq += __shfl_xor(vq,o,64); vb += __shfl_xor(vb,o,64); }
  if (lane == 0){ red[wv] = vq; red[4+wv] = vb; }
  __syncthreads();
  if (tid == 0) gqbq[r*2+0] = red[0]+red[1]+red[2]+red[3];
  if (tid == 1) gqbq[r*2+1] = red[4]+red[5]+red[6]+red[7];
}

// ===== tiled stages (proven round 8): 256 blocks = 8 sg x 32 col-groups of 8 =====

__global__ __launch_bounds__(256) void k_gruF(const float* __restrict__ sin_,
    const float* __restrict__ uacc, const float* __restrict__ Zacc,
    const float* __restrict__ Wf, const float* __restrict__ b_ih,
    const float* __restrict__ ghb, float* __restrict__ hbuf){
  __shared__ float xs[16][260];
  __shared__ float ws[24][260];
  const int tid = threadIdx.x, bid = blockIdx.x;
  const int sg = bid >> 5, cgi = bid & 31, cbase = cgi * 8;
  #pragma unroll
  for (int i = 0; i < 4; ++i){
    int idx4 = tid + i*256, jj = idx4 >> 6, k4 = idx4 & 63;
    *(float4*)&xs[jj][k4*4] = *(const float4*)(uacc + ((size_t)(sg + 8*jj))*256 + k4*4);
  }
  #pragma unroll
  for (int i = 0; i < 6; ++i){
    int idx4 = tid + i*256, row = idx4 >> 6, k4 = idx4 & 63;
    int g = row >> 3, rr = row & 7;
    *(float4*)&ws[row][k4*4] =
      *(const float4*)(Wf + (size_t)(sg*3 + g)*65536 + ((size_t)(cbase + rr))*256 + k4*4);
  }
  __syncthreads();
  if (tid < 128){
    const int j = tid >> 3, cc = tid & 7, r = sg + 8*j, c = cbase + cc;
    float rZ = 1.f / Zacc[r];
    float ir_ = dot256(&ws[cc][0],    &xs[j][0]) * rZ + b_ih[c];
    float iz_ = dot256(&ws[8+cc][0],  &xs[j][0]) * rZ + b_ih[256 + c];
    float in_ = dot256(&ws[16+cc][0], &xs[j][0]) * rZ + b_ih[512 + c];
    float hr_ = ghb[((size_t)0*128 + r)*256 + c];
    float hz_ = ghb[((size_t)1*128 + r)*256 + c];
    float hn_ = ghb[((size_t)2*128 + r)*256 + c];
    float hp  = sin_[(size_t)r*256 + c];
    float rg = 1.f/(1.f + expf(-(ir_ + hr_)));
    float zg = 1.f/(1.f + expf(-(iz_ + hz_)));
    float ng = tanhf(in_ + rg*hn_);
    hbuf[(size_t)r*256 + c] = (1.f - zg)*ng + zg*hp;
  }
}

__global__ __launch_bounds__(256) void k_ffa(const float* __restrict__ hbuf,
    const float* __restrict__ g_ff, const float* __restrict__ be_ff,
    const float* __restrict__ W1, const float* __restrict__ b1,
    float* __restrict__ hid, float* __restrict__ uacc, float* __restrict__ Zacc){
  __shared__ float xs[16][260];
  __shared__ float ws[8][260];
  __shared__ float gA[256], gB[256];
  __shared__ float redA[16][17], redB[16][17];
  __shared__ float musL[16], invsL[16];
  const int tid = threadIdx.x, bid = blockIdx.x;
  const int sg = bid >> 5, cgi = bid & 31, cbase = cgi * 8;
  #pragma unroll
  for (int i = 0; i < 4; ++i){
    int idx4 = tid + i*256, jj = idx4 >> 6, k4 = idx4 & 63;
    *(float4*)&xs[jj][k4*4] = *(const float4*)(hbuf + ((size_t)(sg + 8*jj))*256 + k4*4);
  }
  #pragma unroll
  for (int i = 0; i < 2; ++i){
    int idx4 = tid + i*256, row = idx4 >> 6, k4 = idx4 & 63;
    *(float4*)&ws[row][k4*4] = *(const float4*)(W1 + ((size_t)(cbase + row))*256 + k4*4);
  }
  gA[tid] = g_ff[tid]; gB[tid] = be_ff[tid];
  __syncthreads();
  {
    int jr = tid >> 4, seg = tid & 15;
    float s1 = 0.f, s2 = 0.f;
    #pragma unroll
    for (int i = 0; i < 16; ++i){ float v = xs[jr][seg*16 + i]; s1 += v; s2 += v*v; }
    redA[jr][seg] = s1; redB[jr][seg] = s2;
    __syncthreads();
    if (tid < 16){
      float t1 = 0.f, t2 = 0.f;
      #pragma unroll
      for (int p = 0; p < 16; ++p){ t1 += redA[tid][p]; t2 += redB[tid][p]; }
      float mu = t1 * (1.f/256.f);
      float var = t2 * (1.f/256.f) - mu*mu;
      musL[tid] = mu; invsL[tid] = rsqrtf(var + LN_EPS);
    }
    __syncthreads();
    float mu = musL[jr], inv = invsL[jr];
    #pragma unroll
    for (int i = 0; i < 16; ++i){
      int k = seg*16 + i;
      xs[jr][k] = (xs[jr][k] - mu)*inv*gA[k] + gB[k];
    }
  }
  __syncthreads();
  if (tid < 128){
    const int j = tid >> 3, cc = tid & 7, r = sg + 8*j, c = cbase + cc;
    hid[(size_t)r*256 + c] = fmaxf(dot256(&ws[cc][0], &xs[j][0]) + b1[c], 0.f);
    uacc[(size_t)r*256 + c] = 0.f;
  }
  if (cgi == 0 && tid < 16) Zacc[sg + 8*tid] = 0.f;
}

__global__ __launch_bounds__(256) void k_ffb(const float* __restrict__ hid,
    const float* __restrict__ hbuf, const float* __restrict__ W2,
    const float* __restrict__ b2, float* __restrict__ sout,
    float* __restrict__ out_slots, float* __restrict__ gqbq, int last){
  __shared__ float xs[16][260];
  __shared__ float ws[8][260];
  const int tid = threadIdx.x, bid = blockIdx.x;
  const int sg = bid >> 5, cgi = bid & 31, cbase = cgi * 8;
  #pragma unroll
  for (int i = 0; i < 4; ++i){
    int idx4 = tid + i*256, jj = idx4 >> 6, k4 = idx4 & 63;
    *(float4*)&xs[jj][k4*4] = *(const float4*)(hid + ((size_t)(sg + 8*jj))*256 + k4*4);
  }
  #pragma unroll
  for (int i = 0; i < 2; ++i){
    int idx4 = tid + i*256, row = idx4 >> 6, k4 = idx4 & 63;
    *(float4*)&ws[row][k4*4] = *(const float4*)(W2 + ((size_t)(cbase + row))*256 + k4*4);
  }
  __syncthreads();
  if (tid < 128){
    const int j = tid >> 3, cc = tid & 7, r = sg + 8*j, c = cbase + cc;
    float out = hbuf[(size_t)r*256 + c] + dot256(&ws[cc][0], &xs[j][0]) + b2[c];
    sout[(size_t)r*256 + c] = out;
    if (last) out_slots[(size_t)r*256 + c] = out;
  }
  if (cgi == 0 && tid < 32)
    gqbq[(sg + 8*(tid>>1))*2 + (tid&1)] = 0.f;
}

__global__ __launch_bounds__(256) void k_lnqk(const float* __restrict__ sl,
    const float* __restrict__ g_s, const float* __restrict__ be_s,
    const float* __restrict__ Mt,
    const float* __restrict__ g_in, const float* __restrict__ be_in,
    float* __restrict__ qg, float* __restrict__ gqbq){
  __shared__ float xs[16][260];
  __shared__ float ws[8][260];
  __shared__ float gA[256], gB[256];
  __shared__ float redA[16][17], redB[16][17];
  __shared__ float musL[16], invsL[16];
  const int tid = threadIdx.x, bid = blockIdx.x;
  const int sg = bid >> 5, cgi = bid & 31, cbase = cgi * 8;
  #pragma unroll
  for (int i = 0; i < 4; ++i){
    int idx4 = tid + i*256, jj = idx4 >> 6, k4 = idx4 & 63;
    *(float4*)&xs[jj][k4*4] = *(const float4*)(sl + ((size_t)(sg + 8*jj))*256 + k4*4);
  }
  #pragma unroll
  for (int i = 0; i < 2; ++i){
    int idx4 = tid + i*256, row = idx4 >> 6, k4 = idx4 & 63;
    *(float4*)&ws[row][k4*4] =
      *(const float4*)(Mt + (size_t)sg*65536 + ((size_t)(cbase + row))*256 + k4*4);
  }
  gA[tid] = g_s[tid]; gB[tid] = be_s[tid];
  __syncthreads();
  {
    int jr = tid >> 4, seg = tid & 15;
    float s1 = 0.f, s2 = 0.f;
    #pragma unroll
    for (int i = 0; i < 16; ++i){ float v = xs[jr][seg*16 + i]; s1 += v; s2 += v*v; }
    redA[jr][seg] = s1; redB[jr][seg] = s2;
    __syncthreads();
    if (tid < 16){
      float t1 = 0.f, t2 = 0.f;
      #pragma unroll
      for (int p = 0; p < 16; ++p){ t1 += redA[tid][p]; t2 += redB[tid][p]; }
      float mu = t1 * (1.f/256.f);
      float var = t2 * (1.f/256.f) - mu*mu;
      musL[tid] = mu; invsL[tid] = rsqrtf(var + LN_EPS);
    }
    __syncthreads();
    float mu = musL[jr], inv = invsL[jr];
    #pragma unroll
    for (int i = 0; i < 16; ++i){
      int k = seg*16 + i;
      xs[jr][k] = (xs[jr][k] - mu)*inv*gA[k] + gB[k];
    }
  }
  __syncthreads();
  if (tid < 128){
    const int j = tid >> 3, cc = tid & 7, r = sg + 8*j, c = cbase + cc;
    float qk = dot256(&ws[cc][0], &xs[j][0]);
    float qgv = qk * g_in[c] * SCALE;
    float bqv = qk * be_in[c] * SCALE;
    qg[(size_t)r*256 + c] = qgv;
    float vq = qgv, vb = bqv;
    #pragma unroll
    for (int o = 1; o <= 4; o <<= 1){ vq += __shfl_xor(vq,o,64); vb += __shfl_xor(vb,o,64); }
    if (cc == 0){
      atomicAdd(&gqbq[r*2+0], vq);
      atomicAdd(&gqbq[r*2+1], vb);
    }
  }
}

// ---------------- K1: attn blocks 0..1023 (64-token tiles, deep-MLP)
//                  + gh blocks 1024..2559 (8-row) + (it0) Wf/Mt GEMM 2560..3071 ----------
__global__ __launch_bounds__(256) void k_main_gh(const float* __restrict__ emb,
    const float* __restrict__ qg, const float* __restrict__ gqbq,
    const float* __restrict__ g_in, const float* __restrict__ be_in,
    float* __restrict__ uacc, float* __restrict__ Zacc,
    float* __restrict__ out_attn, int write_attn,
    const float* __restrict__ sin_, const float* __restrict__ W_hh,
    const float* __restrict__ b_hh, float* __restrict__ ghb,
    const float* __restrict__ W_ih, const float* __restrict__ Wv,
    const float* __restrict__ Wk, const float* __restrict__ Wq,
    float* __restrict__ Wf, float* __restrict__ Mt){
  __shared__ float U[4352];                    // 17 KB union
  __shared__ float aL[512];
  __shared__ float red2[2][8][4];
  __shared__ float Zs[8], A2s[8], GqL[8], BqL[8];

  const int tid = threadIdx.x, lane = tid & 63, wv = tid >> 6;
  const int blk = blockIdx.x;

  if (blk >= 2560){
    // ---- Wf/Mt GEMM (it0 only): 64x64 tile, K-slice 32 (At[32][68]+Bs[32][68]) ----
    float (*At)[68] = (float(*)[68])U;             // [32][68]
    float (*Bs)[68] = (float(*)[68])(U + 2176);    // [32][68]
    const int gb = blk - 2560;
    const bool isWf = gb < 384;
    const float *A, *B; float *C;
    int tile;
    if (isWf){
      int gm = gb >> 4; tile = gb & 15;        // gm = s*3+g
      A = W_ih + (size_t)(gm % 3) * 65536;     // [i][e] -> transpose load
      B = Wv   + (size_t)(gm / 3) * 65536;     // [e][j]
      C = Wf   + (size_t)gm * 65536;
    } else {
      int gm = (gb - 384) >> 4; tile = (gb - 384) & 15;
      A = Wk + (size_t)gm * 65536;             // [e][c]
      B = Wq;                                  // [e][d]
      C = Mt + (size_t)gm * 65536;
    }
    const int i0 = (tile >> 2) * 64, j0 = (tile & 3) * 64;
    const int ty = tid >> 4, tx = tid & 15;
    float acc[4][4];
    #pragma unroll
    for (int a = 0; a < 4; ++a)
      #pragma unroll
      for (int b = 0; b < 4; ++b) acc[a][b] = 0.f;
    for (int ko = 0; ko < 256; ko += 32){
      #pragma unroll
      for (int p = 0; p < 2; ++p){
        int idx4 = tid + p*256;
        int e = idx4 >> 4, jl4 = idx4 & 15;
        *(float4*)&Bs[e][jl4*4] = *(const float4*)(B + (size_t)(ko+e)*256 + j0 + jl4*4);
      }
      if (isWf){
        #pragma unroll
        for (int p = 0; p < 2; ++p){
          int idx4 = tid + p*256;
          int il = idx4 >> 3, e4 = idx4 & 7;
          float4 w = *(const float4*)(A + (size_t)(i0+il)*256 + ko + e4*4);
          At[e4*4+0][il] = w.x; At[e4*4+1][il] = w.y;
          At[e4*4+2][il] = w.z; At[e4*4+3][il] = w.w;
        }
      } else {
        #pragma unroll
        for (int p = 0; p < 2; ++p){
          int idx4 = tid + p*256;
          int e = idx4 >> 4, il4 = idx4 & 15;
          *(float4*)&At[e][il4*4] = *(const float4*)(A + (size_t)(ko+e)*256 + i0 + il4*4);
        }
      }
      __syncthreads();
      #pragma unroll 4
      for (int e = 0; e < 32; ++e){
        float4 a4 = *(const float4*)&At[e][ty*4];
        float4 b4 = *(const float4*)&Bs[e][tx*4];
        acc[0][0]+=a4.x*b4.x; acc[0][1]+=a4.x*b4.y; acc[0][2]+=a4.x*b4.z; acc[0][3]+=a4.x*b4.w;
        acc[1][0]+=a4.y*b4.x; acc[1][1]+=a4.y*b4.y; acc[1][2]+=a4.y*b4.z; acc[1][3]+=a4.y*b4.w;
        acc[2][0]+=a4.z*b4.x; acc[2][1]+=a4.z*b4.y; acc[2][2]+=a4.z*b4.z; acc[2][3]+=a4.z*b4.w;
        acc[3][0]+=a4.w*b4.x; acc[3][1]+=a4.w*b4.y; acc[3][2]+=a4.w*b4.z; acc[3][3]+=a4.w*b4.w;
      }
      __syncthreads();
    }
    #pragma unroll
    for (int ii = 0; ii < 4; ++ii)
      *(float4*)(C + (size_t)(i0+ty*4+ii)*256 + j0 + tx*4) =
        make_float4(acc[ii][0], acc[ii][1], acc[ii][2], acc[ii][3]);
    return;
  }

  if (blk >= 1024){
    // ---- gh (8-row blocks): gh[g][r][cbase..+8) = sin@W_hh[g]^T + b_hh[g] ----
    float (*xs)[260]  = (float(*)[260])U;          // [8][260]
    float (*wsh)[260] = (float(*)[260])(U + 2080); // [8][260]
    const int idx = blk - 1024;          // 0..1535
    const int g = idx >> 9, sub = idx & 511;
    const int sg = sub >> 6, rest = sub & 63, rh = rest >> 5, cgi = rest & 31;
    const int cbase = cgi * 8;
    #pragma unroll
    for (int i = 0; i < 2; ++i){
      int idx4 = tid + i*256, jj = idx4 >> 6, k4 = idx4 & 63;
      *(float4*)&xs[jj][k4*4] =
        *(const float4*)(sin_ + ((size_t)(sg + 8*(rh*8 + jj)))*256 + k4*4);
    }
    #pragma unroll
    for (int i = 0; i < 2; ++i){
      int idx4 = tid + i*256, row = idx4 >> 6, k4 = idx4 & 63;
      *(float4*)&wsh[row][k4*4] =
        *(const float4*)(W_hh + (size_t)g*65536 + ((size_t)(cbase + row))*256 + k4*4);
    }
    __syncthreads();
    if (tid < 64){
      const int j = tid >> 3, cc = tid & 7;
      const int r = sg + 8*(rh*8 + j), c = cbase + cc;
      ghb[((size_t)g*128 + r)*256 + c] = dot256(&wsh[cc][0], &xs[j][0]) + b_hh[g*256 + c];
    }
    return;
  }

  // ---- attention: 64-token tile, deep-MLP phase 1+2 ----
  float* const qgL = U;                        // [2048] phase 1 (bank-swizzled)
  float* const avL = U + 2048;                 // [512]  phase 1
  float4* const Sp4 = (float4*)U;              // [1024] float4 phase 2 (overlays)

  const int b = blk >> 6, tile = blk & 63;
  const int n0 = tile * 64;

  {
    const float4* src = (const float4*)(qg + (size_t)b * 2048);
    float4* dst = (float4*)qgL;
    #pragma unroll
    for (int k = 0; k < 2; ++k){
      int w = tid + k*256;
      int s = w >> 6, f = w & 63, qq = f >> 3, j = f & 7;
      dst[s*64 + qq*8 + ((j + qq) & 7)] = src[w];
    }
  }
  if (tid < 8){
    GqL[tid] = gqbq[(b*8 + tid)*2 + 0];
    BqL[tid] = gqbq[(b*8 + tid)*2 + 1];
  }

  const int qq = tid & 7, tq = tid >> 3;
  // preload BOTH passes' rows: 16 outstanding loads cover the softmax chain
  float4 xv4[2][8];
  {
    const float4* xrow0 = (const float4*)(emb + ((size_t)(b*4096 + n0 + tq))*256 + qq*32);
    const float4* xrow1 = (const float4*)(emb + ((size_t)(b*4096 + n0 + 32 + tq))*256 + qq*32);
    #pragma unroll
    for (int j = 0; j < 8; ++j) xv4[0][j] = xrow0[j];
    #pragma unroll
    for (int j = 0; j < 8; ++j) xv4[1][j] = xrow1[j];
  }
  __syncthreads();

  float zsum[8], z2sum[8];
  #pragma unroll
  for (int s = 0; s < 8; ++s){ zsum[s] = 0.f; z2sum[s] = 0.f; }

  #pragma unroll
  for (int pass = 0; pass < 2; ++pass){
    const int t = pass*32 + tq;
    float s1 = 0.f, s2 = 0.f, acc[8];
    #pragma unroll
    for (int s = 0; s < 8; ++s) acc[s] = 0.f;
    #pragma unroll
    for (int j = 0; j < 8; ++j){
      float4 u = xv4[pass][j];
      s1 += (u.x+u.y)+(u.z+u.w);
      s2 += u.x*u.x+u.y*u.y+u.z*u.z+u.w*u.w;
      const float* qb = qgL + qq*32 + ((j + qq) & 7)*4;
      #pragma unroll
      for (int s = 0; s < 8; ++s){
        float4 q0 = *(const float4*)(qb + s*256);
        acc[s] += u.x*q0.x + u.y*q0.y + u.z*q0.z + u.w*q0.w;
      }
    }
    #pragma unroll
    for (int o = 1; o <= 4; o <<= 1){
      s1 += __shfl_xor(s1,o,64); s2 += __shfl_xor(s2,o,64);
      #pragma unroll
      for (int s = 0; s < 8; ++s) acc[s] += __shfl_xor(acc[s],o,64);
    }
    float mu = s1 * (1.f/256.f);
    float var = s2 * (1.f/256.f) - mu*mu;
    float inv = rsqrtf(var + LN_EPS);
    float dv[8], mx = -1e30f;
    #pragma unroll
    for (int s = 0; s < 8; ++s){
      dv[s] = inv * (acc[s] - mu * GqL[s]) + BqL[s];
      mx = fmaxf(mx, dv[s]);
    }
    float den = 0.f;
    #pragma unroll
    for (int s = 0; s < 8; ++s){ dv[s] = expf(dv[s] - mx); den += dv[s]; }
    float rden = 1.f / den;
    #pragma unroll
    for (int s = 0; s < 8; ++s){
      float at = dv[s] * rden;
      float av = at * inv;
      if (qq == 0){ avL[s*64 + t] = at; aL[s*64 + t] = av; }
      zsum[s] += at;
      z2sum[s] += av * mu;
    }
  }
  #pragma unroll
  for (int s = 0; s < 8; ++s){
    #pragma unroll
    for (int o = 32; o; o >>= 1){
      zsum[s] += __shfl_xor(zsum[s], o, 64);
      z2sum[s] += __shfl_xor(z2sum[s], o, 64);
    }
  }
  if (lane == 0){
    #pragma unroll
    for (int s = 0; s < 8; ++s){ red2[0][s][wv] = zsum[s]*0.125f; red2[1][s][wv] = z2sum[s]*0.125f; }
  }
  __syncthreads();
  if (tid < 8){
    Zs[tid]  = red2[0][tid][0]+red2[0][tid][1]+red2[0][tid][2]+red2[0][tid][3];
    A2s[tid] = red2[1][tid][0]+red2[1][tid][1]+red2[1][tid][2]+red2[1][tid][3];
  }
  if (write_attn){
    int s = tid >> 5, tk = tid & 31;
    #pragma unroll
    for (int p = 0; p < 2; ++p)
      out_attn[((size_t)(b*8 + s))*4096 + n0 + p*32 + tk] = avL[s*64 + p*32 + tk];
  }
  __syncthreads();                   // avL/qgL dead past here; Sp4 takes over
  { // phase 2: chunked 8-deep load-then-FMA (2 row-groups x 2 slot-halves)
    const int r2 = tid >> 7, sh = (tid >> 6) & 1, cq = tid & 63;
    float4 S1[4];
    #pragma unroll
    for (int so = 0; so < 4; ++so) S1[so] = make_float4(0.f,0.f,0.f,0.f);
    const float4* xbase = (const float4*)(emb + ((size_t)(b*4096 + n0))*256) + cq;
    #pragma unroll
    for (int ch = 0; ch < 4; ++ch){
      float4 xb[8];
      #pragma unroll
      for (int u = 0; u < 8; ++u) xb[u] = xbase[(size_t)(r2 + (ch*8 + u)*2)*64];
      #pragma unroll
      for (int u = 0; u < 8; ++u){
        int t = r2 + (ch*8 + u)*2;
        #pragma unroll
        for (int so = 0; so < 4; ++so){
          float a = aL[(sh*4+so)*64 + t];   // wave-uniform broadcast
          S1[so].x += a*xb[u].x; S1[so].y += a*xb[u].y;
          S1[so].z += a*xb[u].z; S1[so].w += a*xb[u].w;
        }
      }
    }
    #pragma unroll
    for (int so = 0; so < 4; ++so) Sp4[(r2*8 + sh*4+so)*64 + cq] = S1[so];
  }
  __syncthreads();
  { // final: sum 2 partials per (s,c), atomically accumulate (s staggered)
    const int c = tid;
    const float* Sp = (const float*)Sp4;
    float gc = g_in[c], bc = be_in[c];
    float* dst = uacc + ((size_t)b*8)*256 + c;
    #pragma unroll
    for (int si = 0; si < 8; ++si){
      int s = (si + blk) & 7;
      float v = Sp[(0*8+s)*256 + c] + Sp[(1*8+s)*256 + c];
      atomicAdd(&dst[s*256], gc * (v - A2s[s]) + bc * Zs[s]);
    }
    if (tid < 8) atomicAdd(&Zacc[b*8 + tid], Zs[tid]);
  }
}

extern "C" void kernel_launch(void* const* d_in, const int* in_sizes, int n_in,
                              void* d_out, int out_size, void* d_ws, size_t ws_size,
                              hipStream_t stream){
  const float* emb   = (const float*)d_in[0];
  const float* noise = (const float*)d_in[1];
  const float* smu   = (const float*)d_in[2];
  const float* slsig = (const float*)d_in[3];
  const float* Wk    = (const float*)d_in[4];
  const float* Wq    = (const float*)d_in[5];
  const float* Wv    = (const float*)d_in[6];
  const float* W_ih  = (const float*)d_in[7];
  const float* W_hh  = (const float*)d_in[8];
  const float* b_ih  = (const float*)d_in[9];
  const float* b_hh  = (const float*)d_in[10];
  const float* W1    = (const float*)d_in[11];
  const float* b1    = (const float*)d_in[12];
  const float* W2    = (const float*)d_in[13];
  const float* b2    = (const float*)d_in[14];
  const float* g_in  = (const float*)d_in[15];
  const float* be_in = (const float*)d_in[16];
  const float* g_s   = (const float*)d_in[17];
  const float* be_s  = (const float*)d_in[18];
  const float* g_ff  = (const float*)d_in[19];
  const float* be_ff = (const float*)d_in[20];

  float* ws     = (float*)d_ws;
  float* slotsA = ws;                 // 32768
  float* slotsB = ws + 32768;         // 32768
  float* qg     = ws + 65536;         // 32768
  float* gqbq   = ws + 98304;         // 256
  float* uacc   = ws + 98560;         // 32768
  float* Zacc   = ws + 131328;        // 128
  float* ghb    = ws + 131456;        // 98304
  float* hbuf   = ws + 229760;        // 32768
  float* hid    = ws + 262528;        // 32768
  float* Wf     = ws + 295296;        // 1572864 (6 MB)
  float* Mt     = ws + 1868160;       // 524288  (2 MB)

  float* out_slots = (float*)d_out;
  float* out_attn  = out_slots + 32768;
  const int has_attn = (out_size >= 32768 + 16*8*4096);

  k_initq<<<dim3(128), dim3(256), 0, stream>>>(noise, smu, slsig, slotsA, uacc, Zacc,
      g_s, be_s, Wq, Wk, g_in, be_in, qg, gqbq);
  for (int it = 0; it < 3; ++it){
    int last = (it == 2);
    float* sin  = (it == 1) ? slotsB : slotsA;
    float* sout = (it == 1) ? slotsA : slotsB;
    int grid = (it == 0) ? 3072 : 2560;   // it0 carries the Wf/Mt precompute blocks
    k_main_gh<<<dim3(grid), dim3(256), 0, stream>>>(emb, qg, gqbq, g_in, be_in,
        uacc, Zacc, out_attn, last && has_attn, sin, W_hh, b_hh, ghb,
        W_ih, Wv, Wk, Wq, Wf, Mt);
    k_gruF<<<dim3(256), dim3(256), 0, stream>>>(sin, uacc, Zacc, Wf, b_ih, ghb, hbuf);
    k_ffa<<<dim3(256), dim3(256), 0, stream>>>(hbuf, g_ff, be_ff, W1, b1, hid, uacc, Zacc);
    k_ffb<<<dim3(256), dim3(256), 0, stream>>>(hid, hbuf, W2, b2, sout, out_slots,
        gqbq, last);
    if (!last)
      k_lnqk<<<dim3(256), dim3(256), 0, stream>>>(sout, g_s, be_s, Mt, g_in, be_in,
          qg, gqbq);
  }
}